// Round 2
// baseline (907.442 us; speedup 1.0000x reference)
//
#include <hip/hip_runtime.h>

typedef unsigned int u32;
typedef unsigned short u16;

typedef __attribute__((ext_vector_type(8))) short bf16x8;
typedef __attribute__((ext_vector_type(4))) float f32x4;

__device__ __forceinline__ u16 f2bf(float f) {
  u32 u = __builtin_bit_cast(u32, f);
  u32 r = (u + 0x7fffu + ((u >> 16) & 1u)) >> 16;  // RNE
  return (u16)r;
}
__device__ __forceinline__ float bfl(u32 u) { return __builtin_bit_cast(float, u << 16); }
__device__ __forceinline__ float bfh(u32 u) { return __builtin_bit_cast(float, u & 0xffff0000u); }

// ---------------------------------------------------------------------------
// W_qkv [1536,4608] f32  ->  Wt [4608,1536] bf16   (transpose + convert)
// ---------------------------------------------------------------------------
__global__ __launch_bounds__(256) void transp_wt(const float* __restrict__ W,
                                                 u16* __restrict__ Wt) {
  __shared__ float tile[32][33];
  int bk = blockIdx.x % 48, bn = blockIdx.x / 48;
  int k0 = bk * 32, n0 = bn * 32;
  int tid = threadIdx.x;
#pragma unroll
  for (int p = 0; p < 4; p++) {
    int idx = p * 256 + tid;
    int r = idx >> 5, c = idx & 31;
    tile[r][c] = W[(size_t)(k0 + r) * 4608 + n0 + c];
  }
  __syncthreads();
#pragma unroll
  for (int p = 0; p < 4; p++) {
    int idx = p * 256 + tid;
    int r = idx >> 5, c = idx & 31;
    Wt[(size_t)(n0 + r) * 1536 + k0 + c] = f2bf(tile[c][r]);
  }
}

// ---------------------------------------------------------------------------
// sin_emb = (pos-embedding matrix) @ W_pos  ->  [13, 1536] f32
// emb[f,k] = k<768 ? sin(pos_f*inv_ts[k]) : cos(pos_f*inv_ts[k-768]),
// pos_f = 12 - f
// ---------------------------------------------------------------------------
__global__ __launch_bounds__(256) void pos_emb(const float* __restrict__ Wp,
                                               float* __restrict__ semb) {
  __shared__ float er[1536];
  int f = blockIdx.x / 6;
  int n = (blockIdx.x % 6) * 256 + threadIdx.x;
  float pos = (float)(12 - f);
  const float cfreq = 9.210340371976184f / 767.0f;  // ln(10000)/(nts-1)
  for (int k = threadIdx.x; k < 1536; k += 256) {
    int i = (k < 768) ? k : (k - 768);
    float fr = expf(-cfreq * (float)i);
    float st = pos * fr;
    er[k] = (k < 768) ? sinf(st) : cosf(st);
  }
  __syncthreads();
  float acc = 0.f;
  for (int k = 0; k < 1536; k++) acc = fmaf(er[k], Wp[(size_t)k * 1536 + n], acc);
  semb[f * 1536 + n] = acc;
}

// ---------------------------------------------------------------------------
// qkv = x @ W_qkv (bf16 MFMA), epilogue applies q/k scaling, stores bf16.
// X: [16384,1536] f32 (converted to bf16 during staging)
// Bt: [4608,1536] bf16 (pre-transposed W)
// C:  [16384,4608] bf16
// 128x128 tile, BK=32, 4 waves, each wave 64x64 (4x4 of 16x16x32 frags).
// ---------------------------------------------------------------------------
__global__ __launch_bounds__(256) void gemm_qkv(const float* __restrict__ X,
                                                const u16* __restrict__ Bt,
                                                u16* __restrict__ C,
                                                const float* __restrict__ pds) {
  __shared__ u16 As[128 * 32];
  __shared__ u16 Bs[128 * 32];
  __shared__ float qsc[192];

  int tid = threadIdx.x;
  if (tid < 192) {
    float sp = log1pf(expf(pds[tid]));       // softplus(per_dim_scale)
    qsc[tid] = 0.10411754f * sp;             // * D^-0.5 / ln2
  }

  // supertile swizzle: 8 m-blocks x 36 n-blocks share an A panel via L3
  int bid = blockIdx.x;
  int grp = bid / 288, rem = bid % 288;
  int bm = grp * 8 + rem / 36;
  int bn = rem % 36;
  int m0 = bm * 128, n0 = bn * 128;

  int lane = tid & 63, wv = tid >> 6;
  int wm = (wv >> 1) * 64, wn = (wv & 1) * 64;
  int lr = lane & 15, lk = (lane >> 4) * 8;

  const float* xp[4];
  u16* asp[4];
  const u16* bp[2];
  u16* bsp[2];
#pragma unroll
  for (int p = 0; p < 4; p++) {
    int id = p * 256 + tid;      // 1024 float4 chunks: row=id>>3, q4=id&7
    int row = id >> 3, q4 = id & 7;
    xp[p] = X + (size_t)(m0 + row) * 1536 + q4 * 4;
    asp[p] = &As[row * 32 + q4 * 4];
  }
#pragma unroll
  for (int p = 0; p < 2; p++) {
    int id = p * 256 + tid;      // 512 uint4 chunks: row=id>>2, q=id&3
    int row = id >> 2, q = id & 3;
    bp[p] = Bt + (size_t)(n0 + row) * 1536 + q * 8;
    bsp[p] = &Bs[row * 32 + q * 8];
  }

  f32x4 acc[4][4];
#pragma unroll
  for (int i = 0; i < 4; i++)
#pragma unroll
    for (int j = 0; j < 4; j++) acc[i][j] = (f32x4){0.f, 0.f, 0.f, 0.f};

  for (int kt = 0; kt < 1536; kt += 32) {
    float4 ra[4];
    uint4 rb[2];
#pragma unroll
    for (int p = 0; p < 4; p++) ra[p] = *(const float4*)(xp[p] + kt);
#pragma unroll
    for (int p = 0; p < 2; p++) rb[p] = *(const uint4*)(bp[p] + kt);
    __syncthreads();  // previous iteration's frag reads done
#pragma unroll
    for (int p = 0; p < 4; p++) {
      uint2 pk;
      pk.x = (u32)f2bf(ra[p].x) | ((u32)f2bf(ra[p].y) << 16);
      pk.y = (u32)f2bf(ra[p].z) | ((u32)f2bf(ra[p].w) << 16);
      *(uint2*)asp[p] = pk;
    }
#pragma unroll
    for (int p = 0; p < 2; p++) *(uint4*)bsp[p] = rb[p];
    __syncthreads();

    bf16x8 af[4], bfr[4];
#pragma unroll
    for (int i = 0; i < 4; i++)
      af[i] = *(const bf16x8*)&As[(wm + i * 16 + lr) * 32 + lk];
#pragma unroll
    for (int j = 0; j < 4; j++)
      bfr[j] = *(const bf16x8*)&Bs[(wn + j * 16 + lr) * 32 + lk];
#pragma unroll
    for (int i = 0; i < 4; i++)
#pragma unroll
      for (int j = 0; j < 4; j++)
        acc[i][j] = __builtin_amdgcn_mfma_f32_16x16x32_bf16(af[i], bfr[j],
                                                            acc[i][j], 0, 0, 0);
  }

  // epilogue: scale per output column; C/D layout col=lane&15, row=(lane>>4)*4+r
  int r0 = (lane >> 4) * 4;
  const float kscale = 1.8946361f;  // ln(1+e)/ln2
#pragma unroll
  for (int i = 0; i < 4; i++) {
#pragma unroll
    for (int j = 0; j < 4; j++) {
      int col = n0 + wn + j * 16 + lr;
      float scl;
      if (col < 1536) scl = qsc[col % 192];
      else if (col < 3072) scl = kscale;
      else scl = 1.0f;
      int row = m0 + wm + i * 16 + r0;
#pragma unroll
      for (int r = 0; r < 4; r++)
        C[(size_t)(row + r) * 4608 + col] = f2bf(acc[i][j][r] * scl);
    }
  }
}

// ---------------------------------------------------------------------------
// Attention: one block per (b, u, h). 156 valid (w, f=c-w) logits,
// softcap, softmax over 24 ctx (invalid = -1e9), PV, store f32.
// ---------------------------------------------------------------------------
__global__ __launch_bounds__(256) void attn_kernel(const u16* __restrict__ qkv,
                                                   const float* __restrict__ semb,
                                                   const unsigned char* __restrict__ mask,
                                                   float* __restrict__ out) {
  __shared__ u16 sq[12 * 200];   // pad 192->200 to break bank stride
  __shared__ u16 sk[24 * 200];
  __shared__ u16 sv[24 * 200];
  __shared__ float se[13 * 200];
  __shared__ float lg[12 * 25];
  __shared__ int vld[24];

  int bid = blockIdx.x;
  int h = bid & 7;
  int u = (bid >> 3) % 171;
  int b = bid / (171 * 8);
  int tid = threadIdx.x;

  // lg has 300 entries, blockDim=256: MUST cover all (was the R1 bug —
  // lg[256..299] held stale LDS -> rows w=10,11 leaked prob mass).
  for (int i = tid; i < 12 * 25; i += 256) lg[i] = -1e9f;
  if (tid < 24) {
    int t = u * 12 + tid - 12;
    vld[tid] = (t >= 0 && t < 2048 && mask[b * 2048 + t] == 0) ? 1 : 0;
  }

  const u16* qb = qkv + (size_t)(b * 2048 + u * 12) * 4608 + h * 192;
  for (int idx = tid; idx < 288; idx += 256) {  // q: 12 rows x 24 uint4
    int w = idx / 24, g = idx % 24;
    uint4 val = {0u, 0u, 0u, 0u};
    if (u * 12 + w < 2048) val = *(const uint4*)(qb + (size_t)w * 4608 + g * 8);
    *(uint4*)&sq[w * 200 + g * 8] = val;
  }
  for (int idx = tid; idx < 1152; idx += 256) {  // k then v: 24 rows x 24 uint4
    int kv = idx / 576, r = idx % 576;
    int c = r / 24, g = r % 24;
    int t = u * 12 + c - 12;
    uint4 val = {0u, 0u, 0u, 0u};
    if (t >= 0 && t < 2048)
      val = *(const uint4*)(qkv + (size_t)(b * 2048 + t) * 4608 +
                            (kv ? 3072 : 1536) + h * 192 + g * 8);
    if (kv) *(uint4*)&sv[c * 200 + g * 8] = val;
    else    *(uint4*)&sk[c * 200 + g * 8] = val;
  }
  for (int idx = tid; idx < 624; idx += 256) {  // sin_emb slice: 13 x 48 float4
    int f = idx / 48, g = idx % 48;
    float4 val = *(const float4*)(semb + (size_t)f * 1536 + h * 192 + g * 4);
    *(float4*)&se[f * 200 + g * 4] = val;
  }
  __syncthreads();

  if (tid < 156) {                 // w fastest -> LDS-friendly lane pattern
    int w = tid % 12, f = tid / 12;
    int c = w + f;                 // causal band: f in [0,13)
    if (vld[c]) {
      float ac = 0.f, bd = 0.f;
      const u16* qp = &sq[w * 200];
      const u16* kp = &sk[c * 200];
      const float* sp = &se[f * 200];
#pragma unroll 4
      for (int i = 0; i < 48; i++) {
        uint2 qa = *(const uint2*)(qp + i * 4);
        uint2 kb = *(const uint2*)(kp + i * 4);
        float4 s4 = *(const float4*)(sp + i * 4);
        float q0 = bfl(qa.x), q1 = bfh(qa.x), q2 = bfl(qa.y), q3 = bfh(qa.y);
        float k0 = bfl(kb.x), k1 = bfh(kb.x), k2 = bfl(kb.y), k3 = bfh(kb.y);
        ac = fmaf(q0, k0, fmaf(q1, k1, fmaf(q2, k2, fmaf(q3, k3, ac))));
        bd = fmaf(q0, s4.x, fmaf(q1, s4.y, fmaf(q2, s4.z, fmaf(q3, s4.w, bd))));
      }
      float l = ac + bd;
      l = tanhf(l * 0.02f) * 50.f;  // softcap
      lg[w * 25 + c] = l;
    }
  }
  __syncthreads();

  if (tid < 12) {  // row softmax over 24 ctx; all-invalid -> uniform 1/24 (matches ref)
    float m = -3e38f;
#pragma unroll
    for (int c = 0; c < 24; c++) m = fmaxf(m, lg[tid * 25 + c]);
    float s = 0.f;
#pragma unroll
    for (int c = 0; c < 24; c++) {
      float e = expf(lg[tid * 25 + c] - m);
      lg[tid * 25 + c] = e;
      s += e;
    }
    float inv = 1.f / s;
#pragma unroll
    for (int c = 0; c < 24; c++) lg[tid * 25 + c] *= inv;
  }
  __syncthreads();

  for (int idx = tid; idx < 576; idx += 256) {  // PV: 12 w x 48 (4-elem) chunks
    int w = idx / 48, g = idx % 48;
    float a0 = 0, a1 = 0, a2 = 0, a3 = 0;
#pragma unroll 8
    for (int c = 0; c < 24; c++) {
      float p = lg[w * 25 + c];
      uint2 vv = *(const uint2*)&sv[c * 200 + g * 4];
      a0 = fmaf(p, bfl(vv.x), a0);
      a1 = fmaf(p, bfh(vv.x), a1);
      a2 = fmaf(p, bfl(vv.y), a2);
      a3 = fmaf(p, bfh(vv.y), a3);
    }
    int t = u * 12 + w;
    if (t < 2048) {
      float4 o = {a0, a1, a2, a3};
      *(float4*)&out[(((size_t)(b * 2048 + t)) * 8 + h) * 192 + g * 4] = o;
    }
  }
}

// ---------------------------------------------------------------------------
extern "C" void kernel_launch(void* const* d_in, const int* in_sizes, int n_in,
                              void* d_out, int out_size, void* d_ws, size_t ws_size,
                              hipStream_t stream) {
  (void)in_sizes; (void)n_in; (void)out_size; (void)ws_size;
  const float* x = (const float*)d_in[0];
  const unsigned char* mask = (const unsigned char*)d_in[1];
  // d_in[2] causal_valid_mask: recomputed analytically (c in [w, w+12])
  const float* Wqkv = (const float*)d_in[3];
  const float* Wpos = (const float*)d_in[4];
  const float* pds = (const float*)d_in[5];
  float* out = (float*)d_out;

  char* ws = (char*)d_ws;
  u16* Wt = (u16*)ws;                                   // 28,311,552 B
  u16* qkv = (u16*)(ws + 28311552);                     // 150,994,944 B
  float* semb = (float*)(ws + 28311552 + 150994944);    // 79,872 B

  transp_wt<<<6912, 256, 0, stream>>>(Wqkv, Wt);
  pos_emb<<<78, 256, 0, stream>>>(Wpos, semb);
  gemm_qkv<<<4608, 256, 0, stream>>>(x, Wt, qkv, pds);
  attn_kernel<<<10944, 256, 0, stream>>>(qkv, semb, mask, out);
}

// Round 3
// 470.494 us; speedup vs baseline: 1.9287x; 1.9287x over previous
//
#include <hip/hip_runtime.h>

typedef unsigned int u32;
typedef unsigned short u16;

typedef __attribute__((ext_vector_type(8))) short bf16x8;
typedef __attribute__((ext_vector_type(4))) float f32x4;

__device__ __forceinline__ u16 f2bf(float f) {
  u32 u = __builtin_bit_cast(u32, f);
  u32 r = (u + 0x7fffu + ((u >> 16) & 1u)) >> 16;  // RNE
  return (u16)r;
}
__device__ __forceinline__ float bfl(u32 u) { return __builtin_bit_cast(float, u << 16); }
__device__ __forceinline__ float bfh(u32 u) { return __builtin_bit_cast(float, u & 0xffff0000u); }

__device__ __forceinline__ void gload_lds16(const u16* g, u16* l) {
  __builtin_amdgcn_global_load_lds(
      (const __attribute__((address_space(1))) void*)g,
      (__attribute__((address_space(3))) void*)l, 16, 0, 0);
}

// ---------------------------------------------------------------------------
// W_qkv [1536,4608] f32  ->  Wt [4608,1536] bf16   (transpose + convert)
// ---------------------------------------------------------------------------
__global__ __launch_bounds__(256) void transp_wt(const float* __restrict__ W,
                                                 u16* __restrict__ Wt) {
  __shared__ float tile[32][33];
  int bk = blockIdx.x % 48, bn = blockIdx.x / 48;
  int k0 = bk * 32, n0 = bn * 32;
  int tid = threadIdx.x;
#pragma unroll
  for (int p = 0; p < 4; p++) {
    int idx = p * 256 + tid;
    int r = idx >> 5, c = idx & 31;
    tile[r][c] = W[(size_t)(k0 + r) * 4608 + n0 + c];
  }
  __syncthreads();
#pragma unroll
  for (int p = 0; p < 4; p++) {
    int idx = p * 256 + tid;
    int r = idx >> 5, c = idx & 31;
    Wt[(size_t)(n0 + r) * 1536 + k0 + c] = f2bf(tile[c][r]);
  }
}

// ---------------------------------------------------------------------------
// X [16384*1536] f32 -> bf16 (so gemm can global_load_lds both operands)
// ---------------------------------------------------------------------------
__global__ __launch_bounds__(256) void conv_x(const float* __restrict__ X,
                                              u16* __restrict__ Xb) {
  int i = blockIdx.x * 256 + threadIdx.x;  // one per 8 elems; grid covers exactly
  const float4* xp = (const float4*)X;
  float4 a = xp[i * 2], b = xp[i * 2 + 1];
  uint4 o;
  o.x = (u32)f2bf(a.x) | ((u32)f2bf(a.y) << 16);
  o.y = (u32)f2bf(a.z) | ((u32)f2bf(a.w) << 16);
  o.z = (u32)f2bf(b.x) | ((u32)f2bf(b.y) << 16);
  o.w = (u32)f2bf(b.z) | ((u32)f2bf(b.w) << 16);
  ((uint4*)Xb)[i] = o;
}

// ---------------------------------------------------------------------------
// sin_emb = (pos-embedding matrix) @ W_pos  ->  [13, 1536] f32
// ---------------------------------------------------------------------------
__global__ __launch_bounds__(256) void pos_emb(const float* __restrict__ Wp,
                                               float* __restrict__ semb) {
  __shared__ float er[1536];
  int f = blockIdx.x / 6;
  int n = (blockIdx.x % 6) * 256 + threadIdx.x;
  float pos = (float)(12 - f);
  const float cfreq = 9.210340371976184f / 767.0f;  // ln(10000)/(nts-1)
  for (int k = threadIdx.x; k < 1536; k += 256) {
    int i = (k < 768) ? k : (k - 768);
    float fr = expf(-cfreq * (float)i);
    float st = pos * fr;
    er[k] = (k < 768) ? sinf(st) : cosf(st);
  }
  __syncthreads();
  float acc = 0.f;
  for (int k = 0; k < 1536; k++) acc = fmaf(er[k], Wp[(size_t)k * 1536 + n], acc);
  semb[f * 1536 + n] = acc;
}

// ---------------------------------------------------------------------------
// qkv = Xb @ Wt^T (bf16 MFMA, m97 structure):
//   - global_load_lds dwordx4 staging for A and B (no VALU in staging)
//   - linear LDS dest + XOR-pre-swizzled global source; frag reads apply
//     the same involution -> conflict-free ds_read_b128 (rule #21)
//   - BK=64, 128x128 tile, 4 waves, 2 barriers/K-step, 24 K-steps
//   - epilogue: scale, repack via LDS, coalesced 16B writes
// ---------------------------------------------------------------------------
__global__ __launch_bounds__(256) void gemm_qkv(const u16* __restrict__ Xb,
                                                const u16* __restrict__ Bt,
                                                u16* __restrict__ C,
                                                const float* __restrict__ pds) {
  __shared__ u16 smem[2 * 128 * 64];  // As | Bs; reused as 128x128 C-tile
  u16* As = smem;
  u16* Bs = smem + 128 * 64;
  __shared__ float qsc[192];

  int tid = threadIdx.x;
  if (tid < 192) {
    float sp = log1pf(expf(pds[tid]));  // softplus(per_dim_scale)
    qsc[tid] = 0.10411754f * sp;        // * D^-0.5 / ln2
  }

  // supertile: 8 m-blocks x 36 n-blocks share panels via L2/L3
  int bid = blockIdx.x;
  int grp = bid / 288, rem = bid % 288;
  int bm = grp * 8 + rem / 36;
  int bn = rem % 36;
  int m0 = bm * 128, n0 = bn * 128;

  int lane = tid & 63, wv = tid >> 6;
  int wm = (wv >> 1) * 64, wn = (wv & 1) * 64;
  int lr = lane & 15;
  int lkq = lane >> 4;        // 0..3 -> k-chunk within 32-wide subtile
  int sxor = lr & 7;          // swizzle term (row&7 == lr&7 for 16-aligned bases)

  // staging: chunk = p*256+tid over 1024 16B-chunks; row=chunk>>3, cr=chunk&7
  // LDS slot (row,cr) <- global (row, cr ^ (row&7))
  const u16* gA[4];
  const u16* gB[4];
  u16* lA[4];
  u16* lB[4];
#pragma unroll
  for (int p = 0; p < 4; p++) {
    int chunk = p * 256 + tid;
    int row = chunk >> 3, cr = chunk & 7;
    int crs = cr ^ (row & 7);
    gA[p] = Xb + (size_t)(m0 + row) * 1536 + crs * 8;
    gB[p] = Bt + (size_t)(n0 + row) * 1536 + crs * 8;
    lA[p] = As + chunk * 8;
    lB[p] = Bs + chunk * 8;
  }

  f32x4 acc[4][4];
#pragma unroll
  for (int i = 0; i < 4; i++)
#pragma unroll
    for (int j = 0; j < 4; j++) acc[i][j] = (f32x4){0.f, 0.f, 0.f, 0.f};

  for (int kt = 0; kt < 1536; kt += 64) {
#pragma unroll
    for (int p = 0; p < 4; p++) gload_lds16(gA[p] + kt, lA[p]);
#pragma unroll
    for (int p = 0; p < 4; p++) gload_lds16(gB[p] + kt, lB[p]);
    __syncthreads();  // drains vmcnt -> LDS tiles ready

#pragma unroll
    for (int ks = 0; ks < 2; ks++) {
      bf16x8 af[4], bfr[4];
      int cc = ((ks * 4 + lkq) ^ sxor) * 8;  // swizzled k-chunk offset (u16)
#pragma unroll
      for (int i = 0; i < 4; i++)
        af[i] = *(const bf16x8*)&As[(wm + i * 16 + lr) * 64 + cc];
#pragma unroll
      for (int j = 0; j < 4; j++)
        bfr[j] = *(const bf16x8*)&Bs[(wn + j * 16 + lr) * 64 + cc];
#pragma unroll
      for (int i = 0; i < 4; i++)
#pragma unroll
        for (int j = 0; j < 4; j++)
          acc[i][j] = __builtin_amdgcn_mfma_f32_16x16x32_bf16(af[i], bfr[j],
                                                              acc[i][j], 0, 0, 0);
    }
    __syncthreads();  // frag reads done before next stage overwrites
  }

  // epilogue: scale + pack bf16 into LDS 128x128 tile, then coalesced write
  int r0 = (lane >> 4) * 4;
  const float kscale = 1.8946361f;  // ln(1+e)/ln2
#pragma unroll
  for (int i = 0; i < 4; i++) {
#pragma unroll
    for (int j = 0; j < 4; j++) {
      int col = wn + j * 16 + lr;
      int gcol = n0 + col;
      float scl;
      if (gcol < 1536) scl = qsc[gcol % 192];
      else if (gcol < 3072) scl = kscale;
      else scl = 1.0f;
#pragma unroll
      for (int r = 0; r < 4; r++)
        smem[(wm + i * 16 + r0 + r) * 128 + col] = f2bf(acc[i][j][r] * scl);
    }
  }
  __syncthreads();
#pragma unroll
  for (int p = 0; p < 8; p++) {
    int idx = p * 256 + tid;            // 2048 chunks of 16B
    int row = idx >> 4, cq = idx & 15;  // 16 chunks per 128-col row
    *(uint4*)&C[(size_t)(m0 + row) * 4608 + n0 + cq * 8] =
        *(const uint4*)&smem[row * 128 + cq * 8];
  }
}

// ---------------------------------------------------------------------------
// Attention: one block per (b, u, h). 156 valid (w, f=c-w) logits,
// softcap, softmax over 24 ctx (invalid = -1e9), PV, store f32.
// ---------------------------------------------------------------------------
__global__ __launch_bounds__(256) void attn_kernel(const u16* __restrict__ qkv,
                                                   const float* __restrict__ semb,
                                                   const unsigned char* __restrict__ mask,
                                                   float* __restrict__ out) {
  __shared__ u16 sq[12 * 200];   // pad 192->200 to break bank stride
  __shared__ u16 sk[24 * 200];
  __shared__ u16 sv[24 * 200];
  __shared__ float se[13 * 200];
  __shared__ float lg[12 * 25];
  __shared__ int vld[24];

  int bid = blockIdx.x;
  int h = bid & 7;
  int u = (bid >> 3) % 171;
  int b = bid / (171 * 8);
  int tid = threadIdx.x;

  for (int i = tid; i < 12 * 25; i += 256) lg[i] = -1e9f;
  if (tid < 24) {
    int t = u * 12 + tid - 12;
    vld[tid] = (t >= 0 && t < 2048 && mask[b * 2048 + t] == 0) ? 1 : 0;
  }

  const u16* qb = qkv + (size_t)(b * 2048 + u * 12) * 4608 + h * 192;
  for (int idx = tid; idx < 288; idx += 256) {  // q: 12 rows x 24 uint4
    int w = idx / 24, g = idx % 24;
    uint4 val = {0u, 0u, 0u, 0u};
    if (u * 12 + w < 2048) val = *(const uint4*)(qb + (size_t)w * 4608 + g * 8);
    *(uint4*)&sq[w * 200 + g * 8] = val;
  }
  for (int idx = tid; idx < 1152; idx += 256) {  // k then v: 24 rows x 24 uint4
    int kv = idx / 576, r = idx % 576;
    int c = r / 24, g = r % 24;
    int t = u * 12 + c - 12;
    uint4 val = {0u, 0u, 0u, 0u};
    if (t >= 0 && t < 2048)
      val = *(const uint4*)(qkv + (size_t)(b * 2048 + t) * 4608 +
                            (kv ? 3072 : 1536) + h * 192 + g * 8);
    if (kv) *(uint4*)&sv[c * 200 + g * 8] = val;
    else    *(uint4*)&sk[c * 200 + g * 8] = val;
  }
  for (int idx = tid; idx < 624; idx += 256) {  // sin_emb slice: 13 x 48 float4
    int f = idx / 48, g = idx % 48;
    float4 val = *(const float4*)(semb + (size_t)f * 1536 + h * 192 + g * 4);
    *(float4*)&se[f * 200 + g * 4] = val;
  }
  __syncthreads();

  if (tid < 156) {                 // w fastest -> LDS-friendly lane pattern
    int w = tid % 12, f = tid / 12;
    int c = w + f;                 // causal band: f in [0,13)
    if (vld[c]) {
      float ac = 0.f, bd = 0.f;
      const u16* qp = &sq[w * 200];
      const u16* kp = &sk[c * 200];
      const float* sp = &se[f * 200];
#pragma unroll 4
      for (int i = 0; i < 48; i++) {
        uint2 qa = *(const uint2*)(qp + i * 4);
        uint2 kb = *(const uint2*)(kp + i * 4);
        float4 s4 = *(const float4*)(sp + i * 4);
        float q0 = bfl(qa.x), q1 = bfh(qa.x), q2 = bfl(qa.y), q3 = bfh(qa.y);
        float k0 = bfl(kb.x), k1 = bfh(kb.x), k2 = bfl(kb.y), k3 = bfh(kb.y);
        ac = fmaf(q0, k0, fmaf(q1, k1, fmaf(q2, k2, fmaf(q3, k3, ac))));
        bd = fmaf(q0, s4.x, fmaf(q1, s4.y, fmaf(q2, s4.z, fmaf(q3, s4.w, bd))));
      }
      float l = ac + bd;
      l = tanhf(l * 0.02f) * 50.f;  // softcap
      lg[w * 25 + c] = l;
    }
  }
  __syncthreads();

  if (tid < 12) {  // row softmax over 24 ctx; all-invalid -> uniform (matches ref)
    float m = -3e38f;
#pragma unroll
    for (int c = 0; c < 24; c++) m = fmaxf(m, lg[tid * 25 + c]);
    float s = 0.f;
#pragma unroll
    for (int c = 0; c < 24; c++) {
      float e = expf(lg[tid * 25 + c] - m);
      lg[tid * 25 + c] = e;
      s += e;
    }
    float inv = 1.f / s;
#pragma unroll
    for (int c = 0; c < 24; c++) lg[tid * 25 + c] *= inv;
  }
  __syncthreads();

  for (int idx = tid; idx < 576; idx += 256) {  // PV: 12 w x 48 (4-elem) chunks
    int w = idx / 48, g = idx % 48;
    float a0 = 0, a1 = 0, a2 = 0, a3 = 0;
#pragma unroll 8
    for (int c = 0; c < 24; c++) {
      float p = lg[w * 25 + c];
      uint2 vv = *(const uint2*)&sv[c * 200 + g * 4];
      a0 = fmaf(p, bfl(vv.x), a0);
      a1 = fmaf(p, bfh(vv.x), a1);
      a2 = fmaf(p, bfl(vv.y), a2);
      a3 = fmaf(p, bfh(vv.y), a3);
    }
    int t = u * 12 + w;
    if (t < 2048) {
      float4 o = {a0, a1, a2, a3};
      *(float4*)&out[(((size_t)(b * 2048 + t)) * 8 + h) * 192 + g * 4] = o;
    }
  }
}

// ---------------------------------------------------------------------------
extern "C" void kernel_launch(void* const* d_in, const int* in_sizes, int n_in,
                              void* d_out, int out_size, void* d_ws, size_t ws_size,
                              hipStream_t stream) {
  (void)in_sizes; (void)n_in; (void)out_size; (void)ws_size;
  const float* x = (const float*)d_in[0];
  const unsigned char* mask = (const unsigned char*)d_in[1];
  // d_in[2] causal_valid_mask: recomputed analytically (c in [w, w+12])
  const float* Wqkv = (const float*)d_in[3];
  const float* Wpos = (const float*)d_in[4];
  const float* pds = (const float*)d_in[5];
  float* out = (float*)d_out;

  char* ws = (char*)d_ws;
  u16* Wt = (u16*)ws;                                   // 28,311,552 B
  u16* qkv = (u16*)(ws + 28311552);                     // 150,994,944 B
  float* semb = (float*)(ws + 28311552 + 150994944);    // 79,872 B
  u16* Xb = (u16*)(ws + 28311552 + 150994944 + 79872);  // 50,331,648 B

  transp_wt<<<6912, 256, 0, stream>>>(Wqkv, Wt);
  conv_x<<<12288, 256, 0, stream>>>(x, Xb);
  pos_emb<<<78, 256, 0, stream>>>(Wpos, semb);
  gemm_qkv<<<4608, 256, 0, stream>>>(Xb, Wt, qkv, pds);
  attn_kernel<<<10944, 256, 0, stream>>>(qkv, semb, mask, out);
}

// Round 4
// 445.289 us; speedup vs baseline: 2.0379x; 1.0566x over previous
//
#include <hip/hip_runtime.h>

typedef unsigned int u32;
typedef unsigned short u16;

typedef __attribute__((ext_vector_type(8))) short bf16x8;
typedef __attribute__((ext_vector_type(4))) float f32x4;

__device__ __forceinline__ u16 f2bf(float f) {
  u32 u = __builtin_bit_cast(u32, f);
  u32 r = (u + 0x7fffu + ((u >> 16) & 1u)) >> 16;  // RNE
  return (u16)r;
}
__device__ __forceinline__ float bfl(u32 u) { return __builtin_bit_cast(float, u << 16); }
__device__ __forceinline__ float bfh(u32 u) { return __builtin_bit_cast(float, u & 0xffff0000u); }

__device__ __forceinline__ void gload_lds16(const u16* g, u16* l) {
  __builtin_amdgcn_global_load_lds(
      (const __attribute__((address_space(1))) void*)g,
      (__attribute__((address_space(3))) void*)l, 16, 0, 0);
}

// ---------------------------------------------------------------------------
// W_qkv [1536,4608] f32  ->  Wt [4608,1536] bf16   (transpose + convert)
// ---------------------------------------------------------------------------
__global__ __launch_bounds__(256) void transp_wt(const float* __restrict__ W,
                                                 u16* __restrict__ Wt) {
  __shared__ float tile[32][33];
  int bk = blockIdx.x % 48, bn = blockIdx.x / 48;
  int k0 = bk * 32, n0 = bn * 32;
  int tid = threadIdx.x;
#pragma unroll
  for (int p = 0; p < 4; p++) {
    int idx = p * 256 + tid;
    int r = idx >> 5, c = idx & 31;
    tile[r][c] = W[(size_t)(k0 + r) * 4608 + n0 + c];
  }
  __syncthreads();
#pragma unroll
  for (int p = 0; p < 4; p++) {
    int idx = p * 256 + tid;
    int r = idx >> 5, c = idx & 31;
    Wt[(size_t)(n0 + r) * 1536 + k0 + c] = f2bf(tile[c][r]);
  }
}

// ---------------------------------------------------------------------------
// X [16384*1536] f32 -> bf16
// ---------------------------------------------------------------------------
__global__ __launch_bounds__(256) void conv_x(const float* __restrict__ X,
                                              u16* __restrict__ Xb) {
  int i = blockIdx.x * 256 + threadIdx.x;
  const float4* xp = (const float4*)X;
  float4 a = xp[i * 2], b = xp[i * 2 + 1];
  uint4 o;
  o.x = (u32)f2bf(a.x) | ((u32)f2bf(a.y) << 16);
  o.y = (u32)f2bf(a.z) | ((u32)f2bf(a.w) << 16);
  o.z = (u32)f2bf(b.x) | ((u32)f2bf(b.y) << 16);
  o.w = (u32)f2bf(b.z) | ((u32)f2bf(b.w) << 16);
  ((uint4*)Xb)[i] = o;
}

// ---------------------------------------------------------------------------
// sin_emb = (pos-embedding matrix) @ W_pos  ->  [13, 1536] f32
// ---------------------------------------------------------------------------
__global__ __launch_bounds__(256) void pos_emb(const float* __restrict__ Wp,
                                               float* __restrict__ semb) {
  __shared__ float er[1536];
  int f = blockIdx.x / 6;
  int n = (blockIdx.x % 6) * 256 + threadIdx.x;
  float pos = (float)(12 - f);
  const float cfreq = 9.210340371976184f / 767.0f;
  for (int k = threadIdx.x; k < 1536; k += 256) {
    int i = (k < 768) ? k : (k - 768);
    float fr = expf(-cfreq * (float)i);
    float st = pos * fr;
    er[k] = (k < 768) ? sinf(st) : cosf(st);
  }
  __syncthreads();
  float acc = 0.f;
  for (int k = 0; k < 1536; k++) acc = fmaf(er[k], Wp[(size_t)k * 1536 + n], acc);
  semb[f * 1536 + n] = acc;
}

// ---------------------------------------------------------------------------
// qkv = Xb @ Wt^T : 256x256 tile, BK=64, 8 waves (2Mx4N), 8-phase schedule
// with counted vmcnt(6) (T3+T4), XOR-swizzled LDS (T2), setprio (T5).
//
// LDS (dynamic, 135168 B): 2 buffers x { A[256][64] | B[256][64] } u16,
// reused as [256][264] u16 C-repack tile in the epilogue.
//
// Stage schedule (half-tiles of 128 rows; order B0,B1,A0,A1 per tile):
//   P0(t): issue A1(t+1)   [opposite-parity buffer]
//   P1(t): issue B0(t+2)   [same parity; B reads drained at P0-end barrier]
//   P2(t): issue B1(t+2)
//   P3(t): issue A0(t+2)   [A reads drained at P2-end barrier]
//   vmcnt(6) at P3 end => tile t+1 fully staged, 3 half-tiles in flight.
// Per phase: 16 MFMA (one C-quadrant x K=64). ds_reads: P0=16, P2=8 b128.
// ---------------------------------------------------------------------------
__global__ __launch_bounds__(512, 2) void gemm_qkv(const u16* __restrict__ Xb,
                                                   const u16* __restrict__ Bt,
                                                   u16* __restrict__ C,
                                                   const float* __restrict__ pds) {
  extern __shared__ u16 smem[];

  const int tid = threadIdx.x;
  const int lane = tid & 63;
  const int wv = tid >> 6;   // 0..7
  const int wr = wv >> 2;    // 0..1  m-half
  const int wc = wv & 3;     // 0..3  n-quarter
  const int lr = lane & 15;
  const int lkq = lane >> 4; // 0..3
  const int sx = lr & 7;

  // XCD-affine mapping: 1152 blocks = 8 xcd x (8 bm x 18 bn)
  int bid = blockIdx.x;
  int xcd = bid & 7, idx = bid >> 3;
  int bm = xcd * 8 + idx / 18;
  int bn = idx % 18;
  int m0 = bm * 256, n0 = bn * 256;

  // ---- staging helpers: half-tile = 128 rows x 64 cols = 1024 x 16B chunks
  auto stageA = [&](int half, int T) {
#pragma unroll
    for (int q = 0; q < 2; q++) {
      int ch = q * 512 + tid;
      int r = ch >> 3, cr = ch & 7;
      int crs = cr ^ (r & 7);
      const u16* g = Xb + (size_t)(m0 + half * 128 + r) * 1536 + T * 64 + crs * 8;
      u16* l = smem + (T & 1) * 32768 + half * 8192 + ch * 8;
      gload_lds16(g, l);
    }
  };
  auto stageB = [&](int half, int T) {
#pragma unroll
    for (int q = 0; q < 2; q++) {
      int ch = q * 512 + tid;
      int r = ch >> 3, cr = ch & 7;
      int crs = cr ^ (r & 7);
      const u16* g = Bt + (size_t)(n0 + half * 128 + r) * 1536 + T * 64 + crs * 8;
      u16* l = smem + (T & 1) * 32768 + 16384 + half * 8192 + ch * 8;
      gload_lds16(g, l);
    }
  };

  f32x4 acc[8][4];
#pragma unroll
  for (int i = 0; i < 8; i++)
#pragma unroll
    for (int j = 0; j < 4; j++) acc[i][j] = (f32x4){0.f, 0.f, 0.f, 0.f};

  // prologue: tile0 fully + tile1 {B0,B1,A0}; A1(1) issued at P0(0)
  stageB(0, 0); stageB(1, 0); stageA(0, 0); stageA(1, 0);
  stageB(0, 1); stageB(1, 1); stageA(0, 1);
  asm volatile("s_waitcnt vmcnt(6)" ::: "memory");  // tile0 complete
  __builtin_amdgcn_s_barrier();

  bf16x8 af[8], bfr[8];

  for (int t = 0; t < 24; t++) {
    const int b = (t & 1) * 32768;

    // ---- P0: ds_read A-quad0 (8) + B all (8); stage A1(t+1); MFMA q(0,0)
#pragma unroll
    for (int i = 0; i < 4; i++)
#pragma unroll
      for (int ks = 0; ks < 2; ks++) {
        int R = wr * 128 + i * 16 + lr;
        af[i * 2 + ks] = *(const bf16x8*)&smem[b + R * 64 + ((ks * 4 + lkq) ^ sx) * 8];
      }
#pragma unroll
    for (int j = 0; j < 4; j++)
#pragma unroll
      for (int ks = 0; ks < 2; ks++) {
        int R = wc * 64 + j * 16 + lr;
        bfr[j * 2 + ks] = *(const bf16x8*)&smem[b + 16384 + R * 64 + ((ks * 4 + lkq) ^ sx) * 8];
      }
    if (t < 23) stageA(1, t + 1);
    __builtin_amdgcn_s_barrier();
    __builtin_amdgcn_s_setprio(1);
#pragma unroll
    for (int i = 0; i < 4; i++)
#pragma unroll
      for (int j = 0; j < 2; j++)
#pragma unroll
        for (int ks = 0; ks < 2; ks++)
          acc[i][j] = __builtin_amdgcn_mfma_f32_16x16x32_bf16(af[i * 2 + ks], bfr[j * 2 + ks], acc[i][j], 0, 0, 0);
    __builtin_amdgcn_s_setprio(0);
    __builtin_amdgcn_s_barrier();

    // ---- P1: stage B0(t+2); MFMA q(0,1)  (pure-register)
    if (t < 22) stageB(0, t + 2);
    __builtin_amdgcn_s_barrier();
    __builtin_amdgcn_s_setprio(1);
#pragma unroll
    for (int i = 0; i < 4; i++)
#pragma unroll
      for (int j = 2; j < 4; j++)
#pragma unroll
        for (int ks = 0; ks < 2; ks++)
          acc[i][j] = __builtin_amdgcn_mfma_f32_16x16x32_bf16(af[i * 2 + ks], bfr[j * 2 + ks], acc[i][j], 0, 0, 0);
    __builtin_amdgcn_s_setprio(0);
    __builtin_amdgcn_s_barrier();

    // ---- P2: ds_read A-quad1 (8, overwrite af); stage B1(t+2); MFMA q(1,0)
#pragma unroll
    for (int i = 0; i < 4; i++)
#pragma unroll
      for (int ks = 0; ks < 2; ks++) {
        int R = wr * 128 + 64 + i * 16 + lr;
        af[i * 2 + ks] = *(const bf16x8*)&smem[b + R * 64 + ((ks * 4 + lkq) ^ sx) * 8];
      }
    if (t < 22) stageB(1, t + 2);
    __builtin_amdgcn_s_barrier();
    __builtin_amdgcn_s_setprio(1);
#pragma unroll
    for (int i = 0; i < 4; i++)
#pragma unroll
      for (int j = 0; j < 2; j++)
#pragma unroll
        for (int ks = 0; ks < 2; ks++)
          acc[4 + i][j] = __builtin_amdgcn_mfma_f32_16x16x32_bf16(af[i * 2 + ks], bfr[j * 2 + ks], acc[4 + i][j], 0, 0, 0);
    __builtin_amdgcn_s_setprio(0);
    __builtin_amdgcn_s_barrier();

    // ---- P3: stage A0(t+2); MFMA q(1,1); counted vmcnt; barrier
    if (t < 22) stageA(0, t + 2);
    __builtin_amdgcn_s_barrier();
    __builtin_amdgcn_s_setprio(1);
#pragma unroll
    for (int i = 0; i < 4; i++)
#pragma unroll
      for (int j = 2; j < 4; j++)
#pragma unroll
        for (int ks = 0; ks < 2; ks++)
          acc[4 + i][j] = __builtin_amdgcn_mfma_f32_16x16x32_bf16(af[i * 2 + ks], bfr[j * 2 + ks], acc[4 + i][j], 0, 0, 0);
    __builtin_amdgcn_s_setprio(0);
    if (t < 22) {
      asm volatile("s_waitcnt vmcnt(6)" ::: "memory");  // tile t+1 staged; 3 halves in flight
    } else {
      asm volatile("s_waitcnt vmcnt(0)" ::: "memory");  // tail: drain
    }
    __builtin_amdgcn_s_barrier();
  }

  // ---- epilogue: scale, repack via LDS [256][264], coalesced 16B stores
  const float kscale = 1.8946361f;  // ln(1+e)/ln2
  int r0 = lkq * 4;
  float scl[4];
#pragma unroll
  for (int j = 0; j < 4; j++) {
    int gcol = n0 + wc * 64 + j * 16 + lr;
    float s;
    if (gcol < 1536) s = 0.10411754f * log1pf(expf(pds[gcol % 192]));  // q: pds softplus * D^-.5/ln2
    else if (gcol < 3072) s = kscale;
    else s = 1.0f;
    scl[j] = s;
  }
#pragma unroll
  for (int i = 0; i < 8; i++)
#pragma unroll
    for (int j = 0; j < 4; j++) {
      int row = wr * 128 + i * 16 + r0;
      int col = wc * 64 + j * 16 + lr;
#pragma unroll
      for (int r = 0; r < 4; r++)
        smem[(row + r) * 264 + col] = f2bf(acc[i][j][r] * scl[j]);
    }
  asm volatile("s_waitcnt lgkmcnt(0)" ::: "memory");  // own ds_writes done
  __builtin_amdgcn_s_barrier();
#pragma unroll
  for (int p = 0; p < 16; p++) {
    int idx2 = p * 512 + tid;
    int row = idx2 >> 5, cq = idx2 & 31;
    *(uint4*)&C[(size_t)(m0 + row) * 4608 + n0 + cq * 8] =
        *(const uint4*)&smem[row * 264 + cq * 8];
  }
}

// ---------------------------------------------------------------------------
// Attention: one block per (b, u, h). 156 valid (w, f=c-w) logits,
// softcap, softmax over 24 ctx (invalid = -1e9), PV, store f32.
// ---------------------------------------------------------------------------
__global__ __launch_bounds__(256) void attn_kernel(const u16* __restrict__ qkv,
                                                   const float* __restrict__ semb,
                                                   const unsigned char* __restrict__ mask,
                                                   float* __restrict__ out) {
  __shared__ u16 sq[12 * 200];
  __shared__ u16 sk[24 * 200];
  __shared__ u16 sv[24 * 200];
  __shared__ float se[13 * 200];
  __shared__ float lg[12 * 25];
  __shared__ int vld[24];

  int bid = blockIdx.x;
  int h = bid & 7;
  int u = (bid >> 3) % 171;
  int b = bid / (171 * 8);
  int tid = threadIdx.x;

  for (int i = tid; i < 12 * 25; i += 256) lg[i] = -1e9f;
  if (tid < 24) {
    int t = u * 12 + tid - 12;
    vld[tid] = (t >= 0 && t < 2048 && mask[b * 2048 + t] == 0) ? 1 : 0;
  }

  const u16* qb = qkv + (size_t)(b * 2048 + u * 12) * 4608 + h * 192;
  for (int idx = tid; idx < 288; idx += 256) {
    int w = idx / 24, g = idx % 24;
    uint4 val = {0u, 0u, 0u, 0u};
    if (u * 12 + w < 2048) val = *(const uint4*)(qb + (size_t)w * 4608 + g * 8);
    *(uint4*)&sq[w * 200 + g * 8] = val;
  }
  for (int idx = tid; idx < 1152; idx += 256) {
    int kv = idx / 576, r = idx % 576;
    int c = r / 24, g = r % 24;
    int t = u * 12 + c - 12;
    uint4 val = {0u, 0u, 0u, 0u};
    if (t >= 0 && t < 2048)
      val = *(const uint4*)(qkv + (size_t)(b * 2048 + t) * 4608 +
                            (kv ? 3072 : 1536) + h * 192 + g * 8);
    if (kv) *(uint4*)&sv[c * 200 + g * 8] = val;
    else    *(uint4*)&sk[c * 200 + g * 8] = val;
  }
  for (int idx = tid; idx < 624; idx += 256) {
    int f = idx / 48, g = idx % 48;
    float4 val = *(const float4*)(semb + (size_t)f * 1536 + h * 192 + g * 4);
    *(float4*)&se[f * 200 + g * 4] = val;
  }
  __syncthreads();

  if (tid < 156) {
    int w = tid % 12, f = tid / 12;
    int c = w + f;
    if (vld[c]) {
      float ac = 0.f, bd = 0.f;
      const u16* qp = &sq[w * 200];
      const u16* kp = &sk[c * 200];
      const float* sp = &se[f * 200];
#pragma unroll 4
      for (int i = 0; i < 48; i++) {
        uint2 qa = *(const uint2*)(qp + i * 4);
        uint2 kb = *(const uint2*)(kp + i * 4);
        float4 s4 = *(const float4*)(sp + i * 4);
        float q0 = bfl(qa.x), q1 = bfh(qa.x), q2 = bfl(qa.y), q3 = bfh(qa.y);
        float k0 = bfl(kb.x), k1 = bfh(kb.x), k2 = bfl(kb.y), k3 = bfh(kb.y);
        ac = fmaf(q0, k0, fmaf(q1, k1, fmaf(q2, k2, fmaf(q3, k3, ac))));
        bd = fmaf(q0, s4.x, fmaf(q1, s4.y, fmaf(q2, s4.z, fmaf(q3, s4.w, bd))));
      }
      float l = ac + bd;
      l = tanhf(l * 0.02f) * 50.f;
      lg[w * 25 + c] = l;
    }
  }
  __syncthreads();

  if (tid < 12) {
    float m = -3e38f;
#pragma unroll
    for (int c = 0; c < 24; c++) m = fmaxf(m, lg[tid * 25 + c]);
    float s = 0.f;
#pragma unroll
    for (int c = 0; c < 24; c++) {
      float e = expf(lg[tid * 25 + c] - m);
      lg[tid * 25 + c] = e;
      s += e;
    }
    float inv = 1.f / s;
#pragma unroll
    for (int c = 0; c < 24; c++) lg[tid * 25 + c] *= inv;
  }
  __syncthreads();

  for (int idx = tid; idx < 576; idx += 256) {
    int w = idx / 48, g = idx % 48;
    float a0 = 0, a1 = 0, a2 = 0, a3 = 0;
#pragma unroll 8
    for (int c = 0; c < 24; c++) {
      float p = lg[w * 25 + c];
      uint2 vv = *(const uint2*)&sv[c * 200 + g * 4];
      a0 = fmaf(p, bfl(vv.x), a0);
      a1 = fmaf(p, bfh(vv.x), a1);
      a2 = fmaf(p, bfl(vv.y), a2);
      a3 = fmaf(p, bfh(vv.y), a3);
    }
    int t = u * 12 + w;
    if (t < 2048) {
      float4 o = {a0, a1, a2, a3};
      *(float4*)&out[(((size_t)(b * 2048 + t)) * 8 + h) * 192 + g * 4] = o;
    }
  }
}

// ---------------------------------------------------------------------------
extern "C" void kernel_launch(void* const* d_in, const int* in_sizes, int n_in,
                              void* d_out, int out_size, void* d_ws, size_t ws_size,
                              hipStream_t stream) {
  (void)in_sizes; (void)n_in; (void)out_size; (void)ws_size;
  const float* x = (const float*)d_in[0];
  const unsigned char* mask = (const unsigned char*)d_in[1];
  const float* Wqkv = (const float*)d_in[3];
  const float* Wpos = (const float*)d_in[4];
  const float* pds = (const float*)d_in[5];
  float* out = (float*)d_out;

  char* ws = (char*)d_ws;
  u16* Wt = (u16*)ws;                                   // 28,311,552 B
  u16* qkv = (u16*)(ws + 28311552);                     // 150,994,944 B
  float* semb = (float*)(ws + 28311552 + 150994944);    // 79,872 B
  u16* Xb = (u16*)(ws + 28311552 + 150994944 + 79872);  // 50,331,648 B

  transp_wt<<<6912, 256, 0, stream>>>(Wqkv, Wt);
  conv_x<<<12288, 256, 0, stream>>>(x, Xb);
  pos_emb<<<78, 256, 0, stream>>>(Wpos, semb);
  gemm_qkv<<<1152, 512, 135168, stream>>>(Xb, Wt, qkv, pds);
  attn_kernel<<<10944, 256, 0, stream>>>(qkv, semb, mask, out);
}

// Round 5
// 409.033 us; speedup vs baseline: 2.2185x; 1.0886x over previous
//
#include <hip/hip_runtime.h>

typedef unsigned int u32;
typedef unsigned short u16;

typedef __attribute__((ext_vector_type(8))) short bf16x8;
typedef __attribute__((ext_vector_type(4))) float f32x4;

__device__ __forceinline__ u16 f2bf(float f) {
  u32 u = __builtin_bit_cast(u32, f);
  u32 r = (u + 0x7fffu + ((u >> 16) & 1u)) >> 16;  // RNE
  return (u16)r;
}
__device__ __forceinline__ float bfl(u32 u) { return __builtin_bit_cast(float, u << 16); }
__device__ __forceinline__ float bfh(u32 u) { return __builtin_bit_cast(float, u & 0xffff0000u); }

__device__ __forceinline__ void gload_lds16(const u16* g, u16* l) {
  __builtin_amdgcn_global_load_lds(
      (const __attribute__((address_space(1))) void*)g,
      (__attribute__((address_space(3))) void*)l, 16, 0, 0);
}

// ---------------------------------------------------------------------------
// W_qkv [1536,4608] f32 -> Wt [4608,1536] bf16  (64x64 tiles, float4 I/O)
// ---------------------------------------------------------------------------
__global__ __launch_bounds__(256) void transp_wt(const float* __restrict__ W,
                                                 u16* __restrict__ Wt) {
  __shared__ float tile[64][68];
  int bk = blockIdx.x % 24, bn = blockIdx.x / 24;
  int k0 = bk * 64, n0 = bn * 64;
  int tid = threadIdx.x;
#pragma unroll
  for (int p = 0; p < 4; p++) {
    int idx = p * 256 + tid;
    int r = idx >> 4, c4 = idx & 15;
    *(float4*)&tile[r][c4 * 4] = *(const float4*)&W[(size_t)(k0 + r) * 4608 + n0 + c4 * 4];
  }
  __syncthreads();
#pragma unroll
  for (int p = 0; p < 2; p++) {
    int idx = p * 256 + tid;
    int rn = idx >> 3, kc = idx & 7;
    u16 pk[8];
#pragma unroll
    for (int e = 0; e < 8; e++) pk[e] = f2bf(tile[kc * 8 + e][rn]);
    *(uint4*)&Wt[(size_t)(n0 + rn) * 1536 + k0 + kc * 8] = *(const uint4*)pk;
  }
}

// ---------------------------------------------------------------------------
// X [16384*1536] f32 -> bf16
// ---------------------------------------------------------------------------
__global__ __launch_bounds__(256) void conv_x(const float* __restrict__ X,
                                              u16* __restrict__ Xb) {
  int i = blockIdx.x * 256 + threadIdx.x;
  const float4* xp = (const float4*)X;
  float4 a = xp[i * 2], b = xp[i * 2 + 1];
  uint4 o;
  o.x = (u32)f2bf(a.x) | ((u32)f2bf(a.y) << 16);
  o.y = (u32)f2bf(a.z) | ((u32)f2bf(a.w) << 16);
  o.z = (u32)f2bf(b.x) | ((u32)f2bf(b.y) << 16);
  o.w = (u32)f2bf(b.z) | ((u32)f2bf(b.w) << 16);
  ((uint4*)Xb)[i] = o;
}

// ---------------------------------------------------------------------------
// sembbf[16,1536] bf16: rows 0..12 = (rel-pos sinusoid row f) @ W_pos,
// rows 13..15 = 0 (pad so qsemb's MFMA B-operand is 16-wide).
// ---------------------------------------------------------------------------
__global__ __launch_bounds__(256) void pos_emb(const float* __restrict__ Wp,
                                               u16* __restrict__ sembbf) {
  int f = blockIdx.x / 6;
  int n = (blockIdx.x % 6) * 256 + threadIdx.x;
  if (f >= 13) {  // block-uniform
    sembbf[(size_t)f * 1536 + n] = 0;
    return;
  }
  __shared__ float er[1536];
  float pos = (float)(12 - f);
  const float cfreq = 9.210340371976184f / 767.0f;  // ln(10000)/(nts-1)
  for (int k = threadIdx.x; k < 1536; k += 256) {
    int i = (k < 768) ? k : (k - 768);
    float fr = expf(-cfreq * (float)i);
    float st = pos * fr;
    er[k] = (k < 768) ? sinf(st) : cosf(st);
  }
  __syncthreads();
  float a0 = 0.f, a1 = 0.f, a2 = 0.f, a3 = 0.f;
  for (int k = 0; k < 1536; k += 4) {
    a0 = fmaf(er[k + 0], Wp[(size_t)(k + 0) * 1536 + n], a0);
    a1 = fmaf(er[k + 1], Wp[(size_t)(k + 1) * 1536 + n], a1);
    a2 = fmaf(er[k + 2], Wp[(size_t)(k + 2) * 1536 + n], a2);
    a3 = fmaf(er[k + 3], Wp[(size_t)(k + 3) * 1536 + n], a3);
  }
  sembbf[(size_t)f * 1536 + n] = f2bf((a0 + a1) + (a2 + a3));
}

// ---------------------------------------------------------------------------
// qkv = Xb @ Wt^T : 256x192 tile, BK=64, 8 waves (2Mx4N), 2 phases/K-tile,
// counted vmcnt(3), XOR-swizzled LDS, setprio. Grid 1536 = 6 rounds/CU exact.
//
// LDS (dynamic, 114688 B): 2 x { A[256][64] | B[192][64] } u16;
// reused as [256][200] u16 C-repack tile in the epilogue.
// Stage units: A half (128 rows, 2 loads/thread), B unit (64 rows, 1 load).
//   P0(t): read B(t) all + A(t) rows 0..63 (per wave-half); stage A0,A1(t+1)
//   P1(t): read A(t) rows 64..127 (per wave-half); stage B0,B1,B2(t+2);
//          vmcnt(3) -> tile t+1 complete, B(t+2) in flight.
// WAR safety: B(t) fully consumed by P0 MFMAs (lgkm-drained before P0-end
// barrier) before B(t+2) staged at P1; A(t+1) is opposite-parity buffer.
// ---------------------------------------------------------------------------
__global__ __launch_bounds__(512, 2) void gemm_qkv(const u16* __restrict__ Xb,
                                                   const u16* __restrict__ Bt,
                                                   u16* __restrict__ C,
                                                   const float* __restrict__ pds) {
  extern __shared__ u16 smem[];

  const int tid = threadIdx.x;
  const int lane = tid & 63;
  const int wv = tid >> 6;   // 0..7
  const int wr = wv >> 2;    // 0..1  m-half (128 rows)
  const int wc = wv & 3;     // 0..3  n-quarter (48 cols)
  const int lr = lane & 15;
  const int lkq = lane >> 4; // 0..3
  const int sx = lr & 7;

  // 1536 blocks = 8 xcd x (8 bm x 24 bn)
  int bid = blockIdx.x;
  int xcd = bid & 7, idx = bid >> 3;
  int bm = xcd * 8 + idx / 24;
  int bn = idx % 24;
  int m0 = bm * 256, n0 = bn * 192;

  auto stageA = [&](int half, int T) {  // 128 rows, 2 loads/thread
#pragma unroll
    for (int q = 0; q < 2; q++) {
      int ch = q * 512 + tid;
      int r = ch >> 3, cr = ch & 7;
      int crs = cr ^ (r & 7);
      const u16* g = Xb + (size_t)(m0 + half * 128 + r) * 1536 + T * 64 + crs * 8;
      u16* l = smem + (T & 1) * 28672 + half * 8192 + ch * 8;
      gload_lds16(g, l);
    }
  };
  auto stageB = [&](int unit, int T) {  // 64 rows, 1 load/thread
    int ch = tid;
    int r = ch >> 3, cr = ch & 7;
    int crs = cr ^ (r & 7);
    const u16* g = Bt + (size_t)(n0 + unit * 64 + r) * 1536 + T * 64 + crs * 8;
    u16* l = smem + (T & 1) * 28672 + 16384 + unit * 4096 + ch * 8;
    gload_lds16(g, l);
  };

  f32x4 acc[8][3];
#pragma unroll
  for (int i = 0; i < 8; i++)
#pragma unroll
    for (int j = 0; j < 3; j++) acc[i][j] = (f32x4){0.f, 0.f, 0.f, 0.f};

  // prologue: tile0 full (7 loads) + tile1 B (3 loads)
  stageB(0, 0); stageB(1, 0); stageB(2, 0);
  stageA(0, 0); stageA(1, 0);
  stageB(0, 1); stageB(1, 1); stageB(2, 1);
  asm volatile("s_waitcnt vmcnt(3)" ::: "memory");  // tile0 complete
  __builtin_amdgcn_s_barrier();

  bf16x8 af[8], bfr[6];

  for (int t = 0; t < 24; t++) {
    const int b = (t & 1) * 28672;

    // ---- P0: read B all (6 b128) + A rows 0..63 (4 b128); stage A(t+1)
#pragma unroll
    for (int j = 0; j < 3; j++)
#pragma unroll
      for (int ks = 0; ks < 2; ks++) {
        int R = wc * 48 + j * 16 + lr;
        bfr[j * 2 + ks] = *(const bf16x8*)&smem[b + 16384 + R * 64 + ((ks * 4 + lkq) ^ sx) * 8];
      }
#pragma unroll
    for (int i = 0; i < 4; i++)
#pragma unroll
      for (int ks = 0; ks < 2; ks++) {
        int R = wr * 128 + i * 16 + lr;
        af[i * 2 + ks] = *(const bf16x8*)&smem[b + R * 64 + ((ks * 4 + lkq) ^ sx) * 8];
      }
    if (t < 23) { stageA(0, t + 1); stageA(1, t + 1); }
    __builtin_amdgcn_s_barrier();
    __builtin_amdgcn_s_setprio(1);
#pragma unroll
    for (int i = 0; i < 4; i++)
#pragma unroll
      for (int j = 0; j < 3; j++)
#pragma unroll
        for (int ks = 0; ks < 2; ks++)
          acc[i][j] = __builtin_amdgcn_mfma_f32_16x16x32_bf16(af[i * 2 + ks], bfr[j * 2 + ks], acc[i][j], 0, 0, 0);
    __builtin_amdgcn_s_setprio(0);
    __builtin_amdgcn_s_barrier();

    // ---- P1: read A rows 64..127 (4 b128); stage B(t+2); vmcnt(3)
#pragma unroll
    for (int i = 0; i < 4; i++)
#pragma unroll
      for (int ks = 0; ks < 2; ks++) {
        int R = wr * 128 + 64 + i * 16 + lr;
        af[i * 2 + ks] = *(const bf16x8*)&smem[b + R * 64 + ((ks * 4 + lkq) ^ sx) * 8];
      }
    if (t < 22) { stageB(0, t + 2); stageB(1, t + 2); stageB(2, t + 2); }
    __builtin_amdgcn_s_barrier();
    __builtin_amdgcn_s_setprio(1);
#pragma unroll
    for (int i = 0; i < 4; i++)
#pragma unroll
      for (int j = 0; j < 3; j++)
#pragma unroll
        for (int ks = 0; ks < 2; ks++)
          acc[4 + i][j] = __builtin_amdgcn_mfma_f32_16x16x32_bf16(af[i * 2 + ks], bfr[j * 2 + ks], acc[4 + i][j], 0, 0, 0);
    __builtin_amdgcn_s_setprio(0);
    if (t < 22) {
      asm volatile("s_waitcnt vmcnt(3)" ::: "memory");  // tile t+1 landed
    } else {
      asm volatile("s_waitcnt vmcnt(0)" ::: "memory");  // tail drain
    }
    __builtin_amdgcn_s_barrier();
  }

  // ---- epilogue: scale, repack via LDS [256][200], coalesced 16B stores
  const float kscale = 1.8946361f;  // ln(1+e)/ln2
  float scl[3];
#pragma unroll
  for (int j = 0; j < 3; j++) {
    int gcol = n0 + wc * 48 + j * 16 + lr;
    float s;
    if (gcol < 1536) s = 0.10411754f * log1pf(expf(pds[gcol % 192]));
    else if (gcol < 3072) s = kscale;
    else s = 1.0f;
    scl[j] = s;
  }
  int r0 = lkq * 4;
#pragma unroll
  for (int i = 0; i < 8; i++)
#pragma unroll
    for (int j = 0; j < 3; j++) {
      int row = wr * 128 + i * 16 + r0;
      int col = wc * 48 + j * 16 + lr;
#pragma unroll
      for (int r = 0; r < 4; r++)
        smem[(row + r) * 200 + col] = f2bf(acc[i][j][r] * scl[j]);
    }
  asm volatile("s_waitcnt lgkmcnt(0)" ::: "memory");
  __builtin_amdgcn_s_barrier();
#pragma unroll
  for (int p = 0; p < 12; p++) {
    int idx2 = p * 512 + tid;           // 6144 chunks of 16B
    int row = idx2 / 24, cq = idx2 % 24;
    *(uint4*)&C[(size_t)(m0 + row) * 4608 + n0 + cq * 8] =
        *(const uint4*)&smem[row * 200 + cq * 8];
  }
}

// ---------------------------------------------------------------------------
// bdall[t,h,f] = q[t,h,:] . sembbf[f,h,:]  (f<13), via 16x16x32 MFMA.
// Block = 16 t-rows x 8 waves (wave = head). 6 MFMA per wave.
// ---------------------------------------------------------------------------
__global__ __launch_bounds__(512) void qsemb(const u16* __restrict__ qkv,
                                             const u16* __restrict__ sembbf,
                                             float* __restrict__ bdall) {
  int tid = threadIdx.x;
  int lane = tid & 63;
  int h = tid >> 6;
  int t0 = blockIdx.x * 16;
  int arow = lane & 15, ak = lane >> 4;

  const u16* qp = qkv + (size_t)(t0 + arow) * 4608 + h * 192 + ak * 8;
  const u16* sp = sembbf + (size_t)(lane & 15) * 1536 + h * 192 + ak * 8;

  f32x4 acc = (f32x4){0.f, 0.f, 0.f, 0.f};
#pragma unroll
  for (int kt = 0; kt < 6; kt++) {
    bf16x8 a = *(const bf16x8*)(qp + kt * 32);
    bf16x8 bb = *(const bf16x8*)(sp + kt * 32);
    acc = __builtin_amdgcn_mfma_f32_16x16x32_bf16(a, bb, acc, 0, 0, 0);
  }
  int f = lane & 15;
  int rbase = (lane >> 4) * 4;
  if (f < 13) {
#pragma unroll
    for (int r = 0; r < 4; r++)
      bdall[(size_t)(t0 + rbase + r) * 104 + h * 13 + f] = acc[r];
  }
}

// ---------------------------------------------------------------------------
// Attention: one block per (b, u, h). ac via LDS dots, bd from bdall,
// softcap, softmax over 24 ctx (invalid = -1e9), PV, store f32.
// ---------------------------------------------------------------------------
__global__ __launch_bounds__(256) void attn_kernel(const u16* __restrict__ qkv,
                                                   const float* __restrict__ bdall,
                                                   const unsigned char* __restrict__ mask,
                                                   float* __restrict__ out) {
  __shared__ u16 sq[12 * 200];
  __shared__ u16 sk[24 * 200];
  __shared__ u16 sv[24 * 200];
  __shared__ float lg[12 * 25];
  __shared__ int vld[24];

  int bid = blockIdx.x;
  int h = bid & 7;
  int u = (bid >> 3) % 171;
  int b = bid / (171 * 8);
  int tid = threadIdx.x;

  for (int i = tid; i < 12 * 25; i += 256) lg[i] = -1e9f;
  if (tid < 24) {
    int t = u * 12 + tid - 12;
    vld[tid] = (t >= 0 && t < 2048 && mask[b * 2048 + t] == 0) ? 1 : 0;
  }

  const u16* qb = qkv + (size_t)(b * 2048 + u * 12) * 4608 + h * 192;
  for (int idx = tid; idx < 288; idx += 256) {  // q: 12 rows x 24 uint4
    int w = idx / 24, g = idx % 24;
    uint4 val = {0u, 0u, 0u, 0u};
    if (u * 12 + w < 2048) val = *(const uint4*)(qb + (size_t)w * 4608 + g * 8);
    *(uint4*)&sq[w * 200 + g * 8] = val;
  }
  for (int idx = tid; idx < 1152; idx += 256) {  // k then v: 24 rows x 24 uint4
    int kv = idx / 576, r = idx % 576;
    int c = r / 24, g = r % 24;
    int t = u * 12 + c - 12;
    uint4 val = {0u, 0u, 0u, 0u};
    if (t >= 0 && t < 2048)
      val = *(const uint4*)(qkv + (size_t)(b * 2048 + t) * 4608 +
                            (kv ? 3072 : 1536) + h * 192 + g * 8);
    if (kv) *(uint4*)&sv[c * 200 + g * 8] = val;
    else    *(uint4*)&sk[c * 200 + g * 8] = val;
  }
  __syncthreads();

  if (tid < 156) {
    int w = tid % 12, f = tid / 12;
    int c = w + f;                 // causal band
    if (vld[c]) {
      float ac = 0.f;
      const u16* qp = &sq[w * 200];
      const u16* kp = &sk[c * 200];
#pragma unroll 4
      for (int i = 0; i < 24; i++) {
        uint4 qa = *(const uint4*)(qp + i * 8);
        uint4 kb = *(const uint4*)(kp + i * 8);
        ac = fmaf(bfl(qa.x), bfl(kb.x), ac);
        ac = fmaf(bfh(qa.x), bfh(kb.x), ac);
        ac = fmaf(bfl(qa.y), bfl(kb.y), ac);
        ac = fmaf(bfh(qa.y), bfh(kb.y), ac);
        ac = fmaf(bfl(qa.z), bfl(kb.z), ac);
        ac = fmaf(bfh(qa.z), bfh(kb.z), ac);
        ac = fmaf(bfl(qa.w), bfl(kb.w), ac);
        ac = fmaf(bfh(qa.w), bfh(kb.w), ac);
      }
      int t = u * 12 + w;
      float bd = 0.f;
      if (t < 2048) bd = bdall[(size_t)(b * 2048 + t) * 104 + h * 13 + f];
      float l = ac + bd;
      l = tanhf(l * 0.02f) * 50.f;  // softcap
      lg[w * 25 + c] = l;
    }
  }
  __syncthreads();

  if (tid < 12) {  // row softmax; all-invalid -> uniform (matches ref)
    float m = -3e38f;
#pragma unroll
    for (int c = 0; c < 24; c++) m = fmaxf(m, lg[tid * 25 + c]);
    float s = 0.f;
#pragma unroll
    for (int c = 0; c < 24; c++) {
      float e = expf(lg[tid * 25 + c] - m);
      lg[tid * 25 + c] = e;
      s += e;
    }
    float inv = 1.f / s;
#pragma unroll
    for (int c = 0; c < 24; c++) lg[tid * 25 + c] *= inv;
  }
  __syncthreads();

  for (int idx = tid; idx < 576; idx += 256) {  // PV
    int w = idx / 48, g = idx % 48;
    float a0 = 0, a1 = 0, a2 = 0, a3 = 0;
#pragma unroll 8
    for (int c = 0; c < 24; c++) {
      float p = lg[w * 25 + c];
      uint2 vv = *(const uint2*)&sv[c * 200 + g * 4];
      a0 = fmaf(p, bfl(vv.x), a0);
      a1 = fmaf(p, bfh(vv.x), a1);
      a2 = fmaf(p, bfl(vv.y), a2);
      a3 = fmaf(p, bfh(vv.y), a3);
    }
    int t = u * 12 + w;
    if (t < 2048) {
      float4 o = {a0, a1, a2, a3};
      *(float4*)&out[(((size_t)(b * 2048 + t)) * 8 + h) * 192 + g * 4] = o;
    }
  }
}

// ---------------------------------------------------------------------------
extern "C" void kernel_launch(void* const* d_in, const int* in_sizes, int n_in,
                              void* d_out, int out_size, void* d_ws, size_t ws_size,
                              hipStream_t stream) {
  (void)in_sizes; (void)n_in; (void)out_size; (void)ws_size;
  const float* x = (const float*)d_in[0];
  const unsigned char* mask = (const unsigned char*)d_in[1];
  const float* Wqkv = (const float*)d_in[3];
  const float* Wpos = (const float*)d_in[4];
  const float* pds = (const float*)d_in[5];
  float* out = (float*)d_out;

  char* ws = (char*)d_ws;
  u16* Wt = (u16*)ws;                          // 14,155,776 B
  u16* qkv = (u16*)(ws + 14155776);            // 150,994,944 B
  u16* Xb = (u16*)(ws + 165150720);            // 50,331,648 B
  u16* sembbf = (u16*)(ws + 215482368);        // 49,152 B
  float* bdall = (float*)(ws + 215531520);     // 6,815,744 B

  transp_wt<<<1728, 256, 0, stream>>>(Wqkv, Wt);
  conv_x<<<12288, 256, 0, stream>>>(x, Xb);
  pos_emb<<<96, 256, 0, stream>>>(Wpos, sembbf);
  gemm_qkv<<<1536, 512, 114688, stream>>>(Xb, Wt, qkv, pds);
  qsemb<<<1024, 512, 0, stream>>>(qkv, sembbf, bdall);
  attn_kernel<<<10944, 256, 0, stream>>>(qkv, bdall, mask, out);
}

// Round 7
// 370.162 us; speedup vs baseline: 2.4515x; 1.1050x over previous
//
#include <hip/hip_runtime.h>

typedef unsigned int u32;
typedef unsigned short u16;

typedef __attribute__((ext_vector_type(8))) short bf16x8;
typedef __attribute__((ext_vector_type(4))) float f32x4;

__device__ __forceinline__ u16 f2bf(float f) {
  u32 u = __builtin_bit_cast(u32, f);
  u32 r = (u + 0x7fffu + ((u >> 16) & 1u)) >> 16;  // RNE
  return (u16)r;
}
__device__ __forceinline__ float bfl(u32 u) { return __builtin_bit_cast(float, u << 16); }
__device__ __forceinline__ float bfh(u32 u) { return __builtin_bit_cast(float, u & 0xffff0000u); }

__device__ __forceinline__ void gload_lds16(const u16* g, u16* l) {
  __builtin_amdgcn_global_load_lds(
      (const __attribute__((address_space(1))) void*)g,
      (__attribute__((address_space(3))) void*)l, 16, 0, 0);
}

// ---------------------------------------------------------------------------
// W_qkv [1536,4608] f32 -> Wt [4608,1536] bf16  (64x64 tiles, float4 I/O)
// ---------------------------------------------------------------------------
__global__ __launch_bounds__(256) void transp_wt(const float* __restrict__ W,
                                                 u16* __restrict__ Wt) {
  __shared__ float tile[64][68];
  int bk = blockIdx.x % 24, bn = blockIdx.x / 24;
  int k0 = bk * 64, n0 = bn * 64;
  int tid = threadIdx.x;
#pragma unroll
  for (int p = 0; p < 4; p++) {
    int idx = p * 256 + tid;
    int r = idx >> 4, c4 = idx & 15;
    *(float4*)&tile[r][c4 * 4] = *(const float4*)&W[(size_t)(k0 + r) * 4608 + n0 + c4 * 4];
  }
  __syncthreads();
#pragma unroll
  for (int p = 0; p < 2; p++) {
    int idx = p * 256 + tid;
    int rn = idx >> 3, kc = idx & 7;
    u16 pk[8];
#pragma unroll
    for (int e = 0; e < 8; e++) pk[e] = f2bf(tile[kc * 8 + e][rn]);
    *(uint4*)&Wt[(size_t)(n0 + rn) * 1536 + k0 + kc * 8] = *(const uint4*)pk;
  }
}

// ---------------------------------------------------------------------------
// X [16384*1536] f32 -> bf16
// ---------------------------------------------------------------------------
__global__ __launch_bounds__(256) void conv_x(const float* __restrict__ X,
                                              u16* __restrict__ Xb) {
  int i = blockIdx.x * 256 + threadIdx.x;
  const float4* xp = (const float4*)X;
  float4 a = xp[i * 2], b = xp[i * 2 + 1];
  uint4 o;
  o.x = (u32)f2bf(a.x) | ((u32)f2bf(a.y) << 16);
  o.y = (u32)f2bf(a.z) | ((u32)f2bf(a.w) << 16);
  o.z = (u32)f2bf(b.x) | ((u32)f2bf(b.y) << 16);
  o.w = (u32)f2bf(b.z) | ((u32)f2bf(b.w) << 16);
  ((uint4*)Xb)[i] = o;
}

// ---------------------------------------------------------------------------
// pos-emb stage 1: partial sums over 32-wide k-slices; W_pos read ONCE.
// part[ks][f][n] = sum_{k in slice ks} er[f][k] * Wp[k][n]
// ---------------------------------------------------------------------------
__global__ __launch_bounds__(256) void pos_emb_part(const float* __restrict__ Wp,
                                                    float* __restrict__ part) {
  __shared__ float er[13 * 32];
  int ks = blockIdx.x % 48, nb = blockIdx.x / 48;
  int tid = threadIdx.x;
  int n = nb * 256 + tid;
  const float cfreq = 9.210340371976184f / 767.0f;  // ln(10000)/(nts-1)
  // STRIDED fill (R6 bug: bare `if (tid < 416)` with blockDim=256 left
  // er[256..415] = stale LDS -> f=8..12 rows garbage)
  for (int i = tid; i < 13 * 32; i += 256) {
    int f = i >> 5, kk = i & 31;
    int k = ks * 32 + kk;
    int ii = (k < 768) ? k : (k - 768);
    float fr = expf(-cfreq * (float)ii);
    float st = (float)(12 - f) * fr;
    er[f * 32 + kk] = (k < 768) ? sinf(st) : cosf(st);
  }
  __syncthreads();
  float acc[13];
#pragma unroll
  for (int f = 0; f < 13; f++) acc[f] = 0.f;
  const float* wp = Wp + (size_t)(ks * 32) * 1536 + n;
  for (int kk = 0; kk < 32; kk++) {
    float w = wp[(size_t)kk * 1536];
#pragma unroll
    for (int f = 0; f < 13; f++) acc[f] = fmaf(er[f * 32 + kk], w, acc[f]);
  }
#pragma unroll
  for (int f = 0; f < 13; f++)
    part[((size_t)ks * 13 + f) * 1536 + n] = acc[f];
}

// ---------------------------------------------------------------------------
// pos-emb stage 2: reduce 48 slices -> sembbf [16,1536] bf16 (rows 13..15 = 0)
// ---------------------------------------------------------------------------
__global__ __launch_bounds__(256) void pos_emb_red(const float* __restrict__ part,
                                                   u16* __restrict__ sembbf) {
  int idxg = blockIdx.x * 256 + threadIdx.x;  // < 24576
  int f = idxg / 1536, n = idxg % 1536;
  float s = 0.f;
  if (f < 13)
    for (int ks = 0; ks < 48; ks++)
      s += part[((size_t)ks * 13 + f) * 1536 + n];
  sembbf[idxg] = f2bf(s);
}

// ---------------------------------------------------------------------------
// qkv = Xb @ Wt^T : 256x288 tile, BK=64, 8 waves (4M x 2N -> wave 64x144),
// 3 phases/K-tile (24 MFMA each), XOR-swizzled LDS, setprio.
// Grid 64x16 = 1024 blocks = 4.0 exact rounds/CU.
//
// LDS (dynamic, 151552 B): 2 x { A[256][64] | B[288][64] } u16 (69632 B each
// parity); reused as [256][296] u16 C-repack tile in epilogue.
// Staging: ALL of tile t+1 issued at P0(t) into the OPPOSITE-parity buffer
// (unconditionally WAR-safe: that buffer's last reads were delivered before
// the end-of-(t-1) barrier); single s_waitcnt vmcnt(0) at P2(t) end,
// ~2 phases (~1200 cyc) after issue -> HBM latency covered.
// ---------------------------------------------------------------------------
__global__ __launch_bounds__(512, 2) void gemm_qkv(const u16* __restrict__ Xb,
                                                   const u16* __restrict__ Bt,
                                                   u16* __restrict__ C,
                                                   const float* __restrict__ pds) {
  extern __shared__ u16 smem[];

  const int tid = threadIdx.x;
  const int lane = tid & 63;
  const int wv = tid >> 6;   // 0..7
  const int wr = wv >> 1;    // 0..3  m-quarter (64 rows)
  const int wc = wv & 1;     // 0..1  n-half (144 cols)
  const int lr = lane & 15;
  const int lkq = lane >> 4; // 0..3
  const int sx = lr & 7;

  // 1024 blocks = 8 xcd x (8 bm x 16 bn)
  int bid = blockIdx.x;
  int xcd = bid & 7, idx = bid >> 3;
  int bm = xcd * 8 + idx / 16;
  int bn = idx % 16;
  int m0 = bm * 256, n0 = bn * 288;

  auto stageA = [&](int T) {  // 256 rows x 64 cols = 2048 chunks, 4/thread
#pragma unroll
    for (int q = 0; q < 4; q++) {
      int ch = q * 512 + tid;
      int r = ch >> 3, cr = ch & 7;
      int crs = cr ^ (r & 7);
      const u16* g = Xb + (size_t)(m0 + r) * 1536 + T * 64 + crs * 8;
      u16* l = smem + (T & 1) * 34816 + ch * 8;
      gload_lds16(g, l);
    }
  };
  auto stageB = [&](int T) {  // 288 rows x 64 cols = 2304 chunks, 4.5/thread
#pragma unroll
    for (int q = 0; q < 4; q++) {
      int ch = q * 512 + tid;
      int r = ch >> 3, cr = ch & 7;
      int crs = cr ^ (r & 7);
      const u16* g = Bt + (size_t)(n0 + r) * 1536 + T * 64 + crs * 8;
      u16* l = smem + (T & 1) * 34816 + 16384 + ch * 8;
      gload_lds16(g, l);
    }
    if (tid < 256) {  // waves 0..3: the extra half-unit (wave-uniform branch)
      int ch = 2048 + tid;
      int r = ch >> 3, cr = ch & 7;
      int crs = cr ^ (r & 7);
      const u16* g = Bt + (size_t)(n0 + r) * 1536 + T * 64 + crs * 8;
      u16* l = smem + (T & 1) * 34816 + 16384 + ch * 8;
      gload_lds16(g, l);
    }
  };

  f32x4 acc[4][9];
#pragma unroll
  for (int i = 0; i < 4; i++)
#pragma unroll
    for (int j = 0; j < 9; j++) acc[i][j] = (f32x4){0.f, 0.f, 0.f, 0.f};

  // prologue: tile0 fully staged
  stageA(0); stageB(0);
  asm volatile("s_waitcnt vmcnt(0)" ::: "memory");
  __builtin_amdgcn_s_barrier();

  bf16x8 af[8], bfr[6];

  for (int t = 0; t < 24; t++) {
    const int b = (t & 1) * 34816;

    // ---- P0: read af all (8 b128) + bfr j=0..2 (6); stage tile t+1; MFMA
#pragma unroll
    for (int i = 0; i < 4; i++)
#pragma unroll
      for (int ks = 0; ks < 2; ks++) {
        int R = wr * 64 + i * 16 + lr;
        af[i * 2 + ks] = *(const bf16x8*)&smem[b + R * 64 + ((ks * 4 + lkq) ^ sx) * 8];
      }
#pragma unroll
    for (int j = 0; j < 3; j++)
#pragma unroll
      for (int ks = 0; ks < 2; ks++) {
        int R = wc * 144 + j * 16 + lr;
        bfr[j * 2 + ks] = *(const bf16x8*)&smem[b + 16384 + R * 64 + ((ks * 4 + lkq) ^ sx) * 8];
      }
    if (t < 23) { stageA(t + 1); stageB(t + 1); }
    __builtin_amdgcn_s_barrier();
    __builtin_amdgcn_s_setprio(1);
#pragma unroll
    for (int i = 0; i < 4; i++)
#pragma unroll
      for (int j = 0; j < 3; j++)
#pragma unroll
        for (int ks = 0; ks < 2; ks++)
          acc[i][j] = __builtin_amdgcn_mfma_f32_16x16x32_bf16(af[i * 2 + ks], bfr[j * 2 + ks], acc[i][j], 0, 0, 0);
    __builtin_amdgcn_s_setprio(0);
    __builtin_amdgcn_s_barrier();

    // ---- P1: read bfr j=3..5; MFMA
#pragma unroll
    for (int j = 0; j < 3; j++)
#pragma unroll
      for (int ks = 0; ks < 2; ks++) {
        int R = wc * 144 + (3 + j) * 16 + lr;
        bfr[j * 2 + ks] = *(const bf16x8*)&smem[b + 16384 + R * 64 + ((ks * 4 + lkq) ^ sx) * 8];
      }
    __builtin_amdgcn_s_barrier();
    __builtin_amdgcn_s_setprio(1);
#pragma unroll
    for (int i = 0; i < 4; i++)
#pragma unroll
      for (int j = 0; j < 3; j++)
#pragma unroll
        for (int ks = 0; ks < 2; ks++)
          acc[i][3 + j] = __builtin_amdgcn_mfma_f32_16x16x32_bf16(af[i * 2 + ks], bfr[j * 2 + ks], acc[i][3 + j], 0, 0, 0);
    __builtin_amdgcn_s_setprio(0);
    __builtin_amdgcn_s_barrier();

    // ---- P2: read bfr j=6..8; MFMA; drain staging; tile boundary
#pragma unroll
    for (int j = 0; j < 3; j++)
#pragma unroll
      for (int ks = 0; ks < 2; ks++) {
        int R = wc * 144 + (6 + j) * 16 + lr;
        bfr[j * 2 + ks] = *(const bf16x8*)&smem[b + 16384 + R * 64 + ((ks * 4 + lkq) ^ sx) * 8];
      }
    __builtin_amdgcn_s_barrier();
    __builtin_amdgcn_s_setprio(1);
#pragma unroll
    for (int i = 0; i < 4; i++)
#pragma unroll
      for (int j = 0; j < 3; j++)
#pragma unroll
        for (int ks = 0; ks < 2; ks++)
          acc[i][6 + j] = __builtin_amdgcn_mfma_f32_16x16x32_bf16(af[i * 2 + ks], bfr[j * 2 + ks], acc[i][6 + j], 0, 0, 0);
    __builtin_amdgcn_s_setprio(0);
    asm volatile("s_waitcnt vmcnt(0)" ::: "memory");  // tile t+1 landed (~2 phases after issue)
    __builtin_amdgcn_s_barrier();
  }

  // ---- epilogue: scale, repack via LDS [256][296], coalesced 16B stores
  const float kscale = 1.8946361f;  // ln(1+e)/ln2
  float scl[9];
#pragma unroll
  for (int j = 0; j < 9; j++) {
    int gcol = n0 + wc * 144 + j * 16 + lr;
    float s;
    if (gcol < 1536) s = 0.10411754f * log1pf(expf(pds[gcol % 192]));
    else if (gcol < 3072) s = kscale;
    else s = 1.0f;
    scl[j] = s;
  }
  int r0 = lkq * 4;
#pragma unroll
  for (int i = 0; i < 4; i++)
#pragma unroll
    for (int j = 0; j < 9; j++) {
      int row = wr * 64 + i * 16 + r0;
      int col = wc * 144 + j * 16 + lr;
#pragma unroll
      for (int r = 0; r < 4; r++)
        smem[(row + r) * 296 + col] = f2bf(acc[i][j][r] * scl[j]);
    }
  asm volatile("s_waitcnt lgkmcnt(0)" ::: "memory");
  __builtin_amdgcn_s_barrier();
#pragma unroll
  for (int p = 0; p < 18; p++) {
    int idx2 = p * 512 + tid;           // 9216 chunks of 16B
    int row = idx2 / 36, cq = idx2 % 36;
    *(uint4*)&C[(size_t)(m0 + row) * 4608 + n0 + cq * 8] =
        *(const uint4*)&smem[row * 296 + cq * 8];
  }
}

// ---------------------------------------------------------------------------
// bdall[t,h,f] = q[t,h,:] . sembbf[f,h,:]  (f<13), via 16x16x32 MFMA.
// ---------------------------------------------------------------------------
__global__ __launch_bounds__(512) void qsemb(const u16* __restrict__ qkv,
                                             const u16* __restrict__ sembbf,
                                             float* __restrict__ bdall) {
  int tid = threadIdx.x;
  int lane = tid & 63;
  int h = tid >> 6;
  int t0 = blockIdx.x * 16;
  int arow = lane & 15, ak = lane >> 4;

  const u16* qp = qkv + (size_t)(t0 + arow) * 4608 + h * 192 + ak * 8;
  const u16* sp = sembbf + (size_t)(lane & 15) * 1536 + h * 192 + ak * 8;

  f32x4 acc = (f32x4){0.f, 0.f, 0.f, 0.f};
#pragma unroll
  for (int kt = 0; kt < 6; kt++) {
    bf16x8 a = *(const bf16x8*)(qp + kt * 32);
    bf16x8 bb = *(const bf16x8*)(sp + kt * 32);
    acc = __builtin_amdgcn_mfma_f32_16x16x32_bf16(a, bb, acc, 0, 0, 0);
  }
  int f = lane & 15;
  int rbase = (lane >> 4) * 4;
  if (f < 13) {
#pragma unroll
    for (int r = 0; r < 4; r++)
      bdall[(size_t)(t0 + rbase + r) * 104 + h * 13 + f] = acc[r];
  }
}

// ---------------------------------------------------------------------------
// Attention, band form: one block per (b, u2, h) covering TWO chunks
// (24 queries, 36 ctx rows). Softmax over the 13-wide causal band is exactly
// the reference's 24-wide softmax (off-band terms are exp(-1e9-m) = 0 in
// f32). PV is 13-term. All-band-invalid rows only occur for t>=2048
// (output sliced off) given mask semantics (f=12 key = query itself).
// ---------------------------------------------------------------------------
__global__ __launch_bounds__(256) void attn_kernel(const u16* __restrict__ qkv,
                                                   const float* __restrict__ bdall,
                                                   const unsigned char* __restrict__ mask,
                                                   float* __restrict__ out) {
  __shared__ u16 sq[24 * 200];
  __shared__ u16 sk[36 * 200];
  __shared__ u16 sv[36 * 200];
  __shared__ float lg[24 * 14];
  __shared__ int vld[36];

  int bid = blockIdx.x;
  int h = bid & 7;
  int u2 = (bid >> 3) % 86;
  int b = bid / (86 * 8);
  int tid = threadIdx.x;
  int tbase = u2 * 24;  // t_q = tbase + w;  t_c = tbase + c - 12

  if (tid < 36) {
    int t = tbase + tid - 12;
    vld[tid] = (t >= 0 && t < 2048 && mask[b * 2048 + t] == 0) ? 1 : 0;
  }

  const u16* base = qkv + (size_t)b * 2048 * 4608 + h * 192;
  for (int idx = tid; idx < 576; idx += 256) {  // q: 24 rows x 24 uint4
    int w = idx / 24, g = idx % 24;
    int t = tbase + w;
    uint4 val = {0u, 0u, 0u, 0u};
    if (t < 2048) val = *(const uint4*)(base + (size_t)t * 4608 + g * 8);
    *(uint4*)&sq[w * 200 + g * 8] = val;
  }
  for (int idx = tid; idx < 1728; idx += 256) {  // k,v: 36 rows x 24 uint4 each
    int kv = idx / 864, r = idx % 864;
    int c = r / 24, g = r % 24;
    int t = tbase + c - 12;
    uint4 val = {0u, 0u, 0u, 0u};
    if (t >= 0 && t < 2048)
      val = *(const uint4*)(base + (size_t)t * 4608 + (kv ? 3072 : 1536) + g * 8);
    if (kv) *(uint4*)&sv[c * 200 + g * 8] = val;
    else    *(uint4*)&sk[c * 200 + g * 8] = val;
  }
  __syncthreads();

  for (int idx = tid; idx < 312; idx += 256) {  // logits: 24 w x 13 f
    int w = idx % 24, f = idx / 24;
    int c = w + f;
    int t = tbase + w;
    float l = -1e9f;
    if (vld[c] && t < 2048) {
      float ac = 0.f;
      const u16* qp = &sq[w * 200];
      const u16* kp = &sk[c * 200];
#pragma unroll 4
      for (int i = 0; i < 24; i++) {
        uint4 qa = *(const uint4*)(qp + i * 8);
        uint4 kb = *(const uint4*)(kp + i * 8);
        ac = fmaf(bfl(qa.x), bfl(kb.x), ac);
        ac = fmaf(bfh(qa.x), bfh(kb.x), ac);
        ac = fmaf(bfl(qa.y), bfl(kb.y), ac);
        ac = fmaf(bfh(qa.y), bfh(kb.y), ac);
        ac = fmaf(bfl(qa.z), bfl(kb.z), ac);
        ac = fmaf(bfh(qa.z), bfh(kb.z), ac);
        ac = fmaf(bfl(qa.w), bfl(kb.w), ac);
        ac = fmaf(bfh(qa.w), bfh(kb.w), ac);
      }
      float bd = bdall[(size_t)(b * 2048 + t) * 104 + h * 13 + f];
      l = tanhf((ac + bd) * 0.02f) * 50.f;  // softcap
    }
    lg[w * 14 + f] = l;
  }
  __syncthreads();

  if (tid < 24) {  // band softmax (13 wide)
    float m = -3e38f;
#pragma unroll
    for (int f = 0; f < 13; f++) m = fmaxf(m, lg[tid * 14 + f]);
    float s = 0.f;
#pragma unroll
    for (int f = 0; f < 13; f++) {
      float e = expf(lg[tid * 14 + f] - m);
      lg[tid * 14 + f] = e;
      s += e;
    }
    float inv = 1.f / s;
#pragma unroll
    for (int f = 0; f < 13; f++) lg[tid * 14 + f] *= inv;
  }
  __syncthreads();

  for (int idx = tid; idx < 1152; idx += 256) {  // PV: 24 w x 48 chunks, 13-term
    int w = idx / 48, g = idx % 48;
    int t = tbase + w;
    if (t >= 2048) continue;
    float a0 = 0, a1 = 0, a2 = 0, a3 = 0;
#pragma unroll
    for (int f = 0; f < 13; f++) {
      float p = lg[w * 14 + f];
      uint2 vv = *(const uint2*)&sv[(w + f) * 200 + g * 4];
      a0 = fmaf(p, bfl(vv.x), a0);
      a1 = fmaf(p, bfh(vv.x), a1);
      a2 = fmaf(p, bfl(vv.y), a2);
      a3 = fmaf(p, bfh(vv.y), a3);
    }
    float4 o = {a0, a1, a2, a3};
    *(float4*)&out[(((size_t)(b * 2048 + t)) * 8 + h) * 192 + g * 4] = o;
  }
}

// ---------------------------------------------------------------------------
extern "C" void kernel_launch(void* const* d_in, const int* in_sizes, int n_in,
                              void* d_out, int out_size, void* d_ws, size_t ws_size,
                              hipStream_t stream) {
  (void)in_sizes; (void)n_in; (void)out_size; (void)ws_size;
  const float* x = (const float*)d_in[0];
  const unsigned char* mask = (const unsigned char*)d_in[1];
  const float* Wqkv = (const float*)d_in[3];
  const float* Wpos = (const float*)d_in[4];
  const float* pds = (const float*)d_in[5];
  float* out = (float*)d_out;

  char* ws = (char*)d_ws;
  u16* Wt = (u16*)ws;                          // 14,155,776 B
  u16* qkv = (u16*)(ws + 14155776);            // 150,994,944 B
  u16* Xb = (u16*)(ws + 165150720);            // 50,331,648 B
  u16* sembbf = (u16*)(ws + 215482368);        // 49,152 B
  float* bdall = (float*)(ws + 215531520);     // 6,815,744 B
  float* part = (float*)(ws + 222347264);      // 3,833,856 B

  transp_wt<<<1728, 256, 0, stream>>>(Wqkv, Wt);
  conv_x<<<12288, 256, 0, stream>>>(x, Xb);
  pos_emb_part<<<288, 256, 0, stream>>>(Wpos, part);
  pos_emb_red<<<96, 256, 0, stream>>>(part, sembbf);
  gemm_qkv<<<1024, 512, 151552, stream>>>(Xb, Wt, qkv, pds);
  qsemb<<<1024, 512, 0, stream>>>(qkv, sembbf, bdall);
  attn_kernel<<<5504, 256, 0, stream>>>(qkv, bdall, mask, out);
}

// Round 8
// 358.643 us; speedup vs baseline: 2.5302x; 1.0321x over previous
//
#include <hip/hip_runtime.h>

typedef unsigned int u32;
typedef unsigned short u16;

typedef __attribute__((ext_vector_type(8))) short bf16x8;
typedef __attribute__((ext_vector_type(4))) float f32x4;

__device__ __forceinline__ u16 f2bf(float f) {
  u32 u = __builtin_bit_cast(u32, f);
  u32 r = (u + 0x7fffu + ((u >> 16) & 1u)) >> 16;  // RNE
  return (u16)r;
}
__device__ __forceinline__ float bfl(u32 u) { return __builtin_bit_cast(float, u << 16); }
__device__ __forceinline__ float bfh(u32 u) { return __builtin_bit_cast(float, u & 0xffff0000u); }

__device__ __forceinline__ void gload_lds16(const u16* g, u16* l) {
  __builtin_amdgcn_global_load_lds(
      (const __attribute__((address_space(1))) void*)g,
      (__attribute__((address_space(3))) void*)l, 16, 0, 0);
}

// ---------------------------------------------------------------------------
// W_qkv [1536,4608] f32 -> Wt [4608,1536] bf16  (64x64 tiles, float4 I/O)
// ---------------------------------------------------------------------------
__global__ __launch_bounds__(256) void transp_wt(const float* __restrict__ W,
                                                 u16* __restrict__ Wt) {
  __shared__ float tile[64][68];
  int bk = blockIdx.x % 24, bn = blockIdx.x / 24;
  int k0 = bk * 64, n0 = bn * 64;
  int tid = threadIdx.x;
#pragma unroll
  for (int p = 0; p < 4; p++) {
    int idx = p * 256 + tid;
    int r = idx >> 4, c4 = idx & 15;
    *(float4*)&tile[r][c4 * 4] = *(const float4*)&W[(size_t)(k0 + r) * 4608 + n0 + c4 * 4];
  }
  __syncthreads();
#pragma unroll
  for (int p = 0; p < 2; p++) {
    int idx = p * 256 + tid;
    int rn = idx >> 3, kc = idx & 7;
    u16 pk[8];
#pragma unroll
    for (int e = 0; e < 8; e++) pk[e] = f2bf(tile[kc * 8 + e][rn]);
    *(uint4*)&Wt[(size_t)(n0 + rn) * 1536 + k0 + kc * 8] = *(const uint4*)pk;
  }
}

// ---------------------------------------------------------------------------
// X [16384*1536] f32 -> bf16
// ---------------------------------------------------------------------------
__global__ __launch_bounds__(256) void conv_x(const float* __restrict__ X,
                                              u16* __restrict__ Xb) {
  int i = blockIdx.x * 256 + threadIdx.x;
  const float4* xp = (const float4*)X;
  float4 a = xp[i * 2], b = xp[i * 2 + 1];
  uint4 o;
  o.x = (u32)f2bf(a.x) | ((u32)f2bf(a.y) << 16);
  o.y = (u32)f2bf(a.z) | ((u32)f2bf(a.w) << 16);
  o.z = (u32)f2bf(b.x) | ((u32)f2bf(b.y) << 16);
  o.w = (u32)f2bf(b.z) | ((u32)f2bf(b.w) << 16);
  ((uint4*)Xb)[i] = o;
}

// ---------------------------------------------------------------------------
// pos-emb stage 1: partial sums over 32-wide k-slices; W_pos read ONCE.
// ---------------------------------------------------------------------------
__global__ __launch_bounds__(256) void pos_emb_part(const float* __restrict__ Wp,
                                                    float* __restrict__ part) {
  __shared__ float er[13 * 32];
  int ks = blockIdx.x % 48, nb = blockIdx.x / 48;
  int tid = threadIdx.x;
  int n = nb * 256 + tid;
  const float cfreq = 9.210340371976184f / 767.0f;  // ln(10000)/(nts-1)
  for (int i = tid; i < 13 * 32; i += 256) {  // strided (R6 bug lesson)
    int f = i >> 5, kk = i & 31;
    int k = ks * 32 + kk;
    int ii = (k < 768) ? k : (k - 768);
    float fr = expf(-cfreq * (float)ii);
    float st = (float)(12 - f) * fr;
    er[f * 32 + kk] = (k < 768) ? sinf(st) : cosf(st);
  }
  __syncthreads();
  float acc[13];
#pragma unroll
  for (int f = 0; f < 13; f++) acc[f] = 0.f;
  const float* wp = Wp + (size_t)(ks * 32) * 1536 + n;
  for (int kk = 0; kk < 32; kk++) {
    float w = wp[(size_t)kk * 1536];
#pragma unroll
    for (int f = 0; f < 13; f++) acc[f] = fmaf(er[f * 32 + kk], w, acc[f]);
  }
#pragma unroll
  for (int f = 0; f < 13; f++)
    part[((size_t)ks * 13 + f) * 1536 + n] = acc[f];
}

// ---------------------------------------------------------------------------
// pos-emb stage 2: reduce 48 slices -> sembbf [16,1536] bf16 (rows 13..15 = 0)
// ---------------------------------------------------------------------------
__global__ __launch_bounds__(256) void pos_emb_red(const float* __restrict__ part,
                                                   u16* __restrict__ sembbf) {
  int idxg = blockIdx.x * 256 + threadIdx.x;  // < 24576
  int f = idxg / 1536, n = idxg % 1536;
  float s = 0.f;
  if (f < 13)
    for (int ks = 0; ks < 48; ks++)
      s += part[((size_t)ks * 13 + f) * 1536 + n];
  sembbf[idxg] = f2bf(s);
}

// ---------------------------------------------------------------------------
// qkv = Xb @ Wt^T : 256x192 tile, BK=64, 8 waves (2Mx4N -> wave 128x48),
// 2 phases/K-tile, XOR-swizzled LDS, setprio. Grid 1536 = 6 exact rounds/CU.
//
// R8 change vs R5: A is TRIPLE-buffered and staged 2 tiles ahead (was 1),
// so the steady-state wait vmcnt(7) only ever targets loads issued >=1.5
// tiles (~2500 cyc) earlier -- HBM latency (~900cy) fully covered. R5's
// A(t+1)-at-P0(t) had only ~1 phase of slack (the hypothesized stall).
//
// LDS (dynamic, 147456 B = 144 KB):
//   A: 3 bufs x 16384 u16 (32 KB)   at (T%3)*16384
//   B: 2 bufs x 12288 u16 (24 KB)   at 49152 + (T&1)*12288
//   epilogue reuses [0..51200) as [256][200] u16 C-repack tile.
// Schedule/tile t:
//   P0: read B(t) all (6 b128) + A(t) rows 0..63 of wave-half; stage A(t+2)
//   P1: read A(t) rows 64..127; stage B(t+2); vmcnt(7) [= A(t+1),B(t+1) done]
// WAR: A buf (t+2)%3 last read at tile t-1 (>=2 barriers back). B parity
// (t&1) read at P0(t), delivered before the P0-end barrier all waves crossed.
// ---------------------------------------------------------------------------
__global__ __launch_bounds__(512, 2) void gemm_qkv(const u16* __restrict__ Xb,
                                                   const u16* __restrict__ Bt,
                                                   u16* __restrict__ C,
                                                   const float* __restrict__ pds) {
  extern __shared__ u16 smem[];

  const int tid = threadIdx.x;
  const int lane = tid & 63;
  const int wv = tid >> 6;   // 0..7
  const int wr = wv >> 2;    // 0..1  m-half (128 rows)
  const int wc = wv & 3;     // 0..3  n-quarter (48 cols)
  const int lr = lane & 15;
  const int lkq = lane >> 4; // 0..3
  const int sx = lr & 7;

  // 1536 blocks = 8 xcd x (8 bm x 24 bn)
  int bid = blockIdx.x;
  int xcd = bid & 7, idx = bid >> 3;
  int bm = xcd * 8 + idx / 24;
  int bn = idx % 24;
  int m0 = bm * 256, n0 = bn * 192;

  auto stageA = [&](int T) {  // 256 rows x 8 chunks = 2048, 4 loads/thread
#pragma unroll
    for (int q = 0; q < 4; q++) {
      int ch = q * 512 + tid;
      int r = ch >> 3, cr = ch & 7;
      int crs = cr ^ (r & 7);
      const u16* g = Xb + (size_t)(m0 + r) * 1536 + T * 64 + crs * 8;
      u16* l = smem + (T % 3) * 16384 + ch * 8;
      gload_lds16(g, l);
    }
  };
  auto stageB = [&](int T) {  // 192 rows x 8 chunks = 1536, 3 loads/thread
#pragma unroll
    for (int q = 0; q < 3; q++) {
      int ch = q * 512 + tid;
      int r = ch >> 3, cr = ch & 7;
      int crs = cr ^ (r & 7);
      const u16* g = Bt + (size_t)(n0 + r) * 1536 + T * 64 + crs * 8;
      u16* l = smem + 49152 + (T & 1) * 12288 + ch * 8;
      gload_lds16(g, l);
    }
  };

  f32x4 acc[8][3];
#pragma unroll
  for (int i = 0; i < 8; i++)
#pragma unroll
    for (int j = 0; j < 3; j++) acc[i][j] = (f32x4){0.f, 0.f, 0.f, 0.f};

  // prologue: tiles 0 and 1 fully staged (14 instr/wave)
  stageA(0); stageB(0); stageA(1); stageB(1);
  asm volatile("s_waitcnt vmcnt(7)" ::: "memory");  // tile0 complete
  __builtin_amdgcn_s_barrier();

  bf16x8 af[8], bfr[6];

  for (int t = 0; t < 24; t++) {
    const int ab = (t % 3) * 16384;
    const int bb = 49152 + (t & 1) * 12288;

    // ---- P0: read B all (6 b128) + A rows 0..63 (4); stage A(t+2); MFMA
#pragma unroll
    for (int j = 0; j < 3; j++)
#pragma unroll
      for (int ks = 0; ks < 2; ks++) {
        int R = wc * 48 + j * 16 + lr;
        bfr[j * 2 + ks] = *(const bf16x8*)&smem[bb + R * 64 + ((ks * 4 + lkq) ^ sx) * 8];
      }
#pragma unroll
    for (int i = 0; i < 4; i++)
#pragma unroll
      for (int ks = 0; ks < 2; ks++) {
        int R = wr * 128 + i * 16 + lr;
        af[i * 2 + ks] = *(const bf16x8*)&smem[ab + R * 64 + ((ks * 4 + lkq) ^ sx) * 8];
      }
    if (t < 22) stageA(t + 2);
    __builtin_amdgcn_s_barrier();
    __builtin_amdgcn_s_setprio(1);
#pragma unroll
    for (int i = 0; i < 4; i++)
#pragma unroll
      for (int j = 0; j < 3; j++)
#pragma unroll
        for (int ks = 0; ks < 2; ks++)
          acc[i][j] = __builtin_amdgcn_mfma_f32_16x16x32_bf16(af[i * 2 + ks], bfr[j * 2 + ks], acc[i][j], 0, 0, 0);
    __builtin_amdgcn_s_setprio(0);
    __builtin_amdgcn_s_barrier();

    // ---- P1: read A rows 64..127 (4); stage B(t+2); vmcnt(7)
#pragma unroll
    for (int i = 0; i < 4; i++)
#pragma unroll
      for (int ks = 0; ks < 2; ks++) {
        int R = wr * 128 + 64 + i * 16 + lr;
        af[i * 2 + ks] = *(const bf16x8*)&smem[ab + R * 64 + ((ks * 4 + lkq) ^ sx) * 8];
      }
    if (t < 22) stageB(t + 2);
    __builtin_amdgcn_s_barrier();
    __builtin_amdgcn_s_setprio(1);
#pragma unroll
    for (int i = 0; i < 4; i++)
#pragma unroll
      for (int j = 0; j < 3; j++)
#pragma unroll
        for (int ks = 0; ks < 2; ks++)
          acc[4 + i][j] = __builtin_amdgcn_mfma_f32_16x16x32_bf16(af[i * 2 + ks], bfr[j * 2 + ks], acc[4 + i][j], 0, 0, 0);
    __builtin_amdgcn_s_setprio(0);
    if (t < 22) {
      // older loads (tile t+1) done; this tile's 7 issues stay in flight
      asm volatile("s_waitcnt vmcnt(7)" ::: "memory");
    } else {
      asm volatile("s_waitcnt vmcnt(0)" ::: "memory");  // tail drain
    }
    __builtin_amdgcn_s_barrier();
  }

  // ---- epilogue: scale, repack via LDS [256][200], coalesced 16B stores
  const float kscale = 1.8946361f;  // ln(1+e)/ln2
  float scl[3];
#pragma unroll
  for (int j = 0; j < 3; j++) {
    int gcol = n0 + wc * 48 + j * 16 + lr;
    float s;
    if (gcol < 1536) s = 0.10411754f * log1pf(expf(pds[gcol % 192]));
    else if (gcol < 3072) s = kscale;
    else s = 1.0f;
    scl[j] = s;
  }
  int r0 = lkq * 4;
#pragma unroll
  for (int i = 0; i < 8; i++)
#pragma unroll
    for (int j = 0; j < 3; j++) {
      int row = wr * 128 + i * 16 + r0;
      int col = wc * 48 + j * 16 + lr;
#pragma unroll
      for (int r = 0; r < 4; r++)
        smem[(row + r) * 200 + col] = f2bf(acc[i][j][r] * scl[j]);
    }
  asm volatile("s_waitcnt lgkmcnt(0)" ::: "memory");
  __builtin_amdgcn_s_barrier();
#pragma unroll
  for (int p = 0; p < 12; p++) {
    int idx2 = p * 512 + tid;           // 6144 chunks of 16B
    int row = idx2 / 24, cq = idx2 % 24;
    *(uint4*)&C[(size_t)(m0 + row) * 4608 + n0 + cq * 8] =
        *(const uint4*)&smem[row * 200 + cq * 8];
  }
}

// ---------------------------------------------------------------------------
// bdall[t,h,f] = q[t,h,:] . sembbf[f,h,:]  (f<13), via 16x16x32 MFMA.
// ---------------------------------------------------------------------------
__global__ __launch_bounds__(512) void qsemb(const u16* __restrict__ qkv,
                                             const u16* __restrict__ sembbf,
                                             float* __restrict__ bdall) {
  int tid = threadIdx.x;
  int lane = tid & 63;
  int h = tid >> 6;
  int t0 = blockIdx.x * 16;
  int arow = lane & 15, ak = lane >> 4;

  const u16* qp = qkv + (size_t)(t0 + arow) * 4608 + h * 192 + ak * 8;
  const u16* sp = sembbf + (size_t)(lane & 15) * 1536 + h * 192 + ak * 8;

  f32x4 acc = (f32x4){0.f, 0.f, 0.f, 0.f};
#pragma unroll
  for (int kt = 0; kt < 6; kt++) {
    bf16x8 a = *(const bf16x8*)(qp + kt * 32);
    bf16x8 bb = *(const bf16x8*)(sp + kt * 32);
    acc = __builtin_amdgcn_mfma_f32_16x16x32_bf16(a, bb, acc, 0, 0, 0);
  }
  int f = lane & 15;
  int rbase = (lane >> 4) * 4;
  if (f < 13) {
#pragma unroll
    for (int r = 0; r < 4; r++)
      bdall[(size_t)(t0 + rbase + r) * 104 + h * 13 + f] = acc[r];
  }
}

// ---------------------------------------------------------------------------
// Attention, band form: one block per (b, u2, h) covering TWO chunks
// (24 queries, 36 ctx rows). Band softmax (13-wide) == reference 24-wide
// softmax exactly (off-band terms are 0 in f32 after max-subtract).
// ---------------------------------------------------------------------------
__global__ __launch_bounds__(256) void attn_kernel(const u16* __restrict__ qkv,
                                                   const float* __restrict__ bdall,
                                                   const unsigned char* __restrict__ mask,
                                                   float* __restrict__ out) {
  __shared__ u16 sq[24 * 200];
  __shared__ u16 sk[36 * 200];
  __shared__ u16 sv[36 * 200];
  __shared__ float lg[24 * 14];
  __shared__ int vld[36];

  int bid = blockIdx.x;
  int h = bid & 7;
  int u2 = (bid >> 3) % 86;
  int b = bid / (86 * 8);
  int tid = threadIdx.x;
  int tbase = u2 * 24;  // t_q = tbase + w;  t_c = tbase + c - 12

  if (tid < 36) {
    int t = tbase + tid - 12;
    vld[tid] = (t >= 0 && t < 2048 && mask[b * 2048 + t] == 0) ? 1 : 0;
  }

  const u16* base = qkv + (size_t)b * 2048 * 4608 + h * 192;
  for (int idx = tid; idx < 576; idx += 256) {  // q: 24 rows x 24 uint4
    int w = idx / 24, g = idx % 24;
    int t = tbase + w;
    uint4 val = {0u, 0u, 0u, 0u};
    if (t < 2048) val = *(const uint4*)(base + (size_t)t * 4608 + g * 8);
    *(uint4*)&sq[w * 200 + g * 8] = val;
  }
  for (int idx = tid; idx < 1728; idx += 256) {  // k,v: 36 rows x 24 uint4 each
    int kv = idx / 864, r = idx % 864;
    int c = r / 24, g = r % 24;
    int t = tbase + c - 12;
    uint4 val = {0u, 0u, 0u, 0u};
    if (t >= 0 && t < 2048)
      val = *(const uint4*)(base + (size_t)t * 4608 + (kv ? 3072 : 1536) + g * 8);
    if (kv) *(uint4*)&sv[c * 200 + g * 8] = val;
    else    *(uint4*)&sk[c * 200 + g * 8] = val;
  }
  __syncthreads();

  for (int idx = tid; idx < 312; idx += 256) {  // logits: 24 w x 13 f
    int w = idx % 24, f = idx / 24;
    int c = w + f;
    int t = tbase + w;
    float l = -1e9f;
    if (vld[c] && t < 2048) {
      float ac = 0.f;
      const u16* qp = &sq[w * 200];
      const u16* kp = &sk[c * 200];
#pragma unroll 4
      for (int i = 0; i < 24; i++) {
        uint4 qa = *(const uint4*)(qp + i * 8);
        uint4 kb = *(const uint4*)(kp + i * 8);
        ac = fmaf(bfl(qa.x), bfl(kb.x), ac);
        ac = fmaf(bfh(qa.x), bfh(kb.x), ac);
        ac = fmaf(bfl(qa.y), bfl(kb.y), ac);
        ac = fmaf(bfh(qa.y), bfh(kb.y), ac);
        ac = fmaf(bfl(qa.z), bfl(kb.z), ac);
        ac = fmaf(bfh(qa.z), bfh(kb.z), ac);
        ac = fmaf(bfl(qa.w), bfl(kb.w), ac);
        ac = fmaf(bfh(qa.w), bfh(kb.w), ac);
      }
      float bd = bdall[(size_t)(b * 2048 + t) * 104 + h * 13 + f];
      l = tanhf((ac + bd) * 0.02f) * 50.f;  // softcap
    }
    lg[w * 14 + f] = l;
  }
  __syncthreads();

  if (tid < 24) {  // band softmax (13 wide)
    float m = -3e38f;
#pragma unroll
    for (int f = 0; f < 13; f++) m = fmaxf(m, lg[tid * 14 + f]);
    float s = 0.f;
#pragma unroll
    for (int f = 0; f < 13; f++) {
      float e = expf(lg[tid * 14 + f] - m);
      lg[tid * 14 + f] = e;
      s += e;
    }
    float inv = 1.f / s;
#pragma unroll
    for (int f = 0; f < 13; f++) lg[tid * 14 + f] *= inv;
  }
  __syncthreads();

  for (int idx = tid; idx < 1152; idx += 256) {  // PV: 24 w x 48 chunks, 13-term
    int w = idx / 48, g = idx % 48;
    int t = tbase + w;
    if (t >= 2048) continue;
    float a0 = 0, a1 = 0, a2 = 0, a3 = 0;
#pragma unroll
    for (int f = 0; f < 13; f++) {
      float p = lg[w * 14 + f];
      uint2 vv = *(const uint2*)&sv[(w + f) * 200 + g * 4];
      a0 = fmaf(p, bfl(vv.x), a0);
      a1 = fmaf(p, bfh(vv.x), a1);
      a2 = fmaf(p, bfl(vv.y), a2);
      a3 = fmaf(p, bfh(vv.y), a3);
    }
    float4 o = {a0, a1, a2, a3};
    *(float4*)&out[(((size_t)(b * 2048 + t)) * 8 + h) * 192 + g * 4] = o;
  }
}

// ---------------------------------------------------------------------------
extern "C" void kernel_launch(void* const* d_in, const int* in_sizes, int n_in,
                              void* d_out, int out_size, void* d_ws, size_t ws_size,
                              hipStream_t stream) {
  (void)in_sizes; (void)n_in; (void)out_size; (void)ws_size;
  const float* x = (const float*)d_in[0];
  const unsigned char* mask = (const unsigned char*)d_in[1];
  const float* Wqkv = (const float*)d_in[3];
  const float* Wpos = (const float*)d_in[4];
  const float* pds = (const float*)d_in[5];
  float* out = (float*)d_out;

  char* ws = (char*)d_ws;
  u16* Wt = (u16*)ws;                          // 14,155,776 B
  u16* qkv = (u16*)(ws + 14155776);            // 150,994,944 B
  u16* Xb = (u16*)(ws + 165150720);            // 50,331,648 B
  u16* sembbf = (u16*)(ws + 215482368);        // 49,152 B
  float* bdall = (float*)(ws + 215531520);     // 6,815,744 B
  float* part = (float*)(ws + 222347264);      // 3,833,856 B

  transp_wt<<<1728, 256, 0, stream>>>(Wqkv, Wt);
  conv_x<<<12288, 256, 0, stream>>>(x, Xb);
  pos_emb_part<<<288, 256, 0, stream>>>(Wpos, part);
  pos_emb_red<<<96, 256, 0, stream>>>(part, sembbf);
  gemm_qkv<<<1536, 512, 147456, stream>>>(Xb, Wt, qkv, pds);
  qsemb<<<1024, 512, 0, stream>>>(qkv, sembbf, bdall);
  attn_kernel<<<5504, 256, 0, stream>>>(qkv, bdall, mask, out);
}